// Round 18
// baseline (171.880 us; speedup 1.0000x reference)
//
#include <hip/hip_runtime.h>
#include <math.h>

#define BATCH 64
#define APB 512
#define NA 6
#define NG 5832  // 18^3

__device__ __forceinline__ float leaky(float v){ return v >= 0.f ? v : 0.01f*v; }

// ============ atom sort: deterministic counting sort by (batch, type) ============
__global__ __launch_bounds__(64) void atom_sort(const float* __restrict__ x,
                                                int* __restrict__ dst,
                                                int* __restrict__ seg_start,
                                                int* __restrict__ seg_count)
{
  int batch = blockIdx.x;
  int lane  = threadIdx.x;
  int tyc[8];
  int cnt[NA];
  #pragma unroll
  for (int t = 0; t < NA; t++) cnt[t] = 0;
  #pragma unroll
  for (int c = 0; c < 8; c++){
    int a = batch*APB + c*64 + lane;
    int ty = (int)x[(size_t)a*5 + 1];
    tyc[c] = ty;
    #pragma unroll
    for (int t = 0; t < NA; t++){
      unsigned long long m = __ballot(ty == t);
      cnt[t] += __popcll(m);
    }
  }
  int pre[NA+1];
  pre[0] = 0;
  #pragma unroll
  for (int t = 0; t < NA; t++) pre[t+1] = pre[t] + cnt[t];
  if (lane < NA){
    seg_start[batch*NA + lane] = batch*APB + pre[lane];
    seg_count[batch*NA + lane] = cnt[lane];
  }
  int run[NA];
  #pragma unroll
  for (int t = 0; t < NA; t++) run[t] = pre[t];
  unsigned long long below = (lane == 0) ? 0ull : ((~0ull) >> (64 - lane));
  #pragma unroll
  for (int c = 0; c < 8; c++){
    int a = batch*APB + c*64 + lane;
    int ty = tyc[c];
    int rank = 0;
    #pragma unroll
    for (int t = 0; t < NA; t++){
      unsigned long long m = __ballot(ty == t);
      if (ty == t) rank = run[t] + __popcll(m & below);
      run[t] += __popcll(m);
    }
    dst[a] = batch*APB + rank;
  }
}

// ============ blur phase 1: per-atom separable 1-D tables (sorted rows) ============
__global__ __launch_bounds__(256) void blur_prep(const float* __restrict__ x,
                                                 const int* __restrict__ dst,
                                                 float* __restrict__ tab)
{
  int a = blockIdx.x*256 + threadIdx.x;
  if (a >= BATCH*APB) return;
  const float* row = x + (size_t)a*5;
  float p0 = row[2], p1 = row[3], p2 = row[4];
  float e[54];
  float s0 = 0.f, s1 = 0.f, s2 = 0.f;
  #pragma unroll
  for (int i = 0; i < 18; i++){
    float g = (float)i - 8.5f;
    float d0 = p0 - g, d1 = p1 - g, d2 = p2 - g;
    float v0 = __expf(d0*d0 * (-1.f/0.72f));
    float v1 = __expf(d1*d1 * (-1.f/0.72f));
    float v2 = __expf(d2*d2 * (-1.f/0.72f));
    e[i] = v0; e[18+i] = v1; e[36+i] = v2;
    s0 += v0; s1 += v1; s2 += v2;
  }
  float inv = 1.f / (s0*s1*s2 + 1e-6f);
  float* tp = tab + (size_t)dst[a]*64;
  #pragma unroll
  for (int i = 0; i < 18; i++) tp[i] = e[i]*inv;
  tp[18] = 0.f; tp[19] = 0.f;
  #pragma unroll
  for (int i = 0; i < 18; i++) tp[20+i] = e[18+i];
  #pragma unroll
  for (int i = 0; i < 18; i++) tp[40+i] = e[36+i];
}

// ============ blur phase 2: branch-free streaming outer-product ============
__global__ __launch_bounds__(192) void blur_accum(const float* __restrict__ tab,
                                                  const int* __restrict__ seg_start,
                                                  const int* __restrict__ seg_count,
                                                  float* __restrict__ fields)
{
  int bid  = blockIdx.x;
  int seg  = bid >> 1;
  int half = bid & 1;
  int tid = threadIdx.x;
  bool act = tid < 162;
  int ix = half*9 + tid/18;
  int iy = tid % 18;

  float acc[18];
  #pragma unroll
  for (int k = 0; k < 18; k++) acc[k] = 0.f;

  int start = seg_start[seg], count = seg_count[seg];
  const float* tb = tab + (size_t)start*64;

  int j = 0;
  for (; j + 3 < count; j += 4){
    const float* t0 = tb + (size_t)(j+0)*64;
    const float* t1 = tb + (size_t)(j+1)*64;
    const float* t2 = tb + (size_t)(j+2)*64;
    const float* t3 = tb + (size_t)(j+3)*64;
    float e0 = t0[ix]*t0[20+iy];
    float e1 = t1[ix]*t1[20+iy];
    float e2 = t2[ix]*t2[20+iy];
    float e3 = t3[ix]*t3[20+iy];
    #pragma unroll
    for (int k = 0; k < 18; k++){
      float a = acc[k];
      a = fmaf(e0, t0[40+k], a);
      a = fmaf(e1, t1[40+k], a);
      a = fmaf(e2, t2[40+k], a);
      a = fmaf(e3, t3[40+k], a);
      acc[k] = a;
    }
  }
  for (; j < count; j++){
    const float* t0 = tb + (size_t)j*64;
    float e0 = t0[ix]*t0[20+iy];
    #pragma unroll
    for (int k = 0; k < 18; k++)
      acc[k] = fmaf(e0, t0[40+k], acc[k]);
  }
  if (act){
    float* fo = fields + (size_t)seg*NG + (size_t)(ix*18 + iy)*18;
    #pragma unroll
    for (int k = 0; k < 18; k++) fo[k] = acc[k];
  }
}

// ============ transpose fields[b*6+t][z*324+y*18+x] -> ft[t][z][y][xq][b][4xr] ============
__global__ __launch_bounds__(256) void transpose_fields(const float* __restrict__ fields,
                                                        float* __restrict__ ft)
{
  __shared__ float tile[64*162];
  int bid = blockIdx.x;           // t*36 + gz*2 + gyh
  int t = bid / 36; int r = bid - t*36;
  int gz = r >> 1, gyh = r & 1;
  int tid = threadIdx.x;

  for (int idx = tid; idx < 64*162; idx += 256){
    int b = idx / 162; int c = idx - b*162;
    tile[idx] = fields[(size_t)(b*NA + t)*NG + gz*324 + gyh*162 + c];
  }
  __syncthreads();
  for (int idx = tid; idx < 9*5*64; idx += 256){
    int r2 = idx >> 6; int b = idx & 63;
    int gy = r2 / 5, xq = r2 - gy*5;
    int x0 = xq*4;
    const float* tp = &tile[b*162 + gy*18];
    float4 v;
    v.x = (x0   < 18) ? tp[x0]   : 0.f;
    v.y = (x0+1 < 18) ? tp[x0+1] : 0.f;
    v.z = (x0+2 < 18) ? tp[x0+2] : 0.f;
    v.w = (x0+3 < 18) ? tp[x0+3] : 0.f;
    *(float4*)(ft + ((((size_t)t*18 + gz)*18 + (gyh*9+gy))*5 + xq)*256 + b*4) = v;
  }
}

// ============ conv0: 6->16; block=(oc,sp,xh), 2 waves = ic-halves (3 ic each);
// xh branch hoisted; straight-line clamped rows + uniform weight-zeroing ============
__global__ __launch_bounds__(128) void conv0t_kernel(const float* __restrict__ ft,
                                                     const float* __restrict__ w,
                                                     const float* __restrict__ bias,
                                                     float* __restrict__ out,   // [16][9][9][3xq][64][4]
                                                     float* __restrict__ part)  // [16*162][2]
{
  __shared__ float red[40*64];           // 10 KB: wave-1 partial acc
  int bid = blockIdx.x;                  // 0..2591
  int l = (bid & 7)*324 + (bid >> 3);    // XCD-aware bijection (2592 = 8*324)
  int oc = l & 15, xh = (l >> 4) & 1;
  int sp = l >> 5;                       // 0..80
  int pz = sp / 9, py = sp - pz*9;
  int tid = threadIdx.x;
  int wid = tid >> 6, lane = tid & 63;

  float acc[2][2][10];
  #pragma unroll
  for (int i=0;i<2;i++)
    #pragma unroll
    for (int j=0;j<2;j++)
      #pragma unroll
      for (int k=0;k<10;k++) acc[i][j][k]=0.f;

  if (xh == 0){
    #pragma unroll
    for (int icl = 0; icl < 3; icl++){
      int ic = wid*3 + icl;
      float wr[27];
      #pragma unroll
      for (int k = 0; k < 27; k++) wr[k] = w[(oc*6+ic)*27 + k];
      #pragma unroll
      for (int zl = 0; zl < 4; zl++){
        int gz = 2*pz - 1 + zl;
        bool vz = ((unsigned)gz < 18u);
        int gzc = vz ? gz : (gz < 0 ? 0 : 17);
        #pragma unroll
        for (int yl = 0; yl < 4; yl++){
          int gy = 2*py - 1 + yl;
          bool v = vz && ((unsigned)gy < 18u);
          int gyc = ((unsigned)gy < 18u) ? gy : (gy < 0 ? 0 : 17);
          const float* rp = ft + (((size_t)ic*18 + gzc)*18 + gyc)*5*256 + lane*4;
          float4 A0 = *(const float4*)(rp);
          float4 A1 = *(const float4*)(rp + 256);
          float4 A2 = *(const float4*)(rp + 512);
          float xv[13];
          xv[0] = 0.f;
          *(float4*)&xv[1] = A0; *(float4*)&xv[5] = A1; *(float4*)&xv[9] = A2;
          #pragma unroll
          for (int czl = 0; czl < 2; czl++){
            const int dz = zl - czl; if (dz < 0 || dz > 2) continue;
            #pragma unroll
            for (int cyl = 0; cyl < 2; cyl++){
              const int dy = yl - cyl; if (dy < 0 || dy > 2) continue;
              const int wb = dz*9 + dy*3;
              const float w0 = v ? wr[wb]   : 0.f;   // uniform select (SALU)
              const float w1 = v ? wr[wb+1] : 0.f;
              const float w2 = v ? wr[wb+2] : 0.f;
              #pragma unroll
              for (int cx = 0; cx < 10; cx++){
                float a = acc[czl][cyl][cx];
                a = fmaf(xv[cx],   w0, a);
                a = fmaf(xv[cx+1], w1, a);
                a = fmaf(xv[cx+2], w2, a);
                acc[czl][cyl][cx] = a;
              }
            }
          }
        }
      }
    }
  } else {
    #pragma unroll
    for (int icl = 0; icl < 3; icl++){
      int ic = wid*3 + icl;
      float wr[27];
      #pragma unroll
      for (int k = 0; k < 27; k++) wr[k] = w[(oc*6+ic)*27 + k];
      #pragma unroll
      for (int zl = 0; zl < 4; zl++){
        int gz = 2*pz - 1 + zl;
        bool vz = ((unsigned)gz < 18u);
        int gzc = vz ? gz : (gz < 0 ? 0 : 17);
        #pragma unroll
        for (int yl = 0; yl < 4; yl++){
          int gy = 2*py - 1 + yl;
          bool v = vz && ((unsigned)gy < 18u);
          int gyc = ((unsigned)gy < 18u) ? gy : (gy < 0 ? 0 : 17);
          const float* rp = ft + (((size_t)ic*18 + gzc)*18 + gyc)*5*256 + lane*4;
          float4 A2 = *(const float4*)(rp + 512);
          float4 A3 = *(const float4*)(rp + 768);
          float4 A4 = *(const float4*)(rp + 1024);
          float win[12];                            // win[j] = p(9+j); p18,p19 stored zero
          *(float4*)&win[0] = A2; *(float4*)&win[4] = A3; *(float4*)&win[8] = A4;
          #pragma unroll
          for (int czl = 0; czl < 2; czl++){
            const int dz = zl - czl; if (dz < 0 || dz > 2) continue;
            #pragma unroll
            for (int cyl = 0; cyl < 2; cyl++){
              const int dy = yl - cyl; if (dy < 0 || dy > 2) continue;
              const int wb = dz*9 + dy*3;
              const float w0 = v ? wr[wb]   : 0.f;
              const float w1 = v ? wr[wb+1] : 0.f;
              const float w2 = v ? wr[wb+2] : 0.f;
              #pragma unroll
              for (int cl = 0; cl < 8; cl++){       // cx = 10+cl
                float a = acc[czl][cyl][cl];
                a = fmaf(win[cl+1], w0, a);
                a = fmaf(win[cl+2], w1, a);
                a = fmaf(win[cl+3], w2, a);
                acc[czl][cyl][cl] = a;
              }
            }
          }
        }
      }
    }
  }

  if (wid == 1){
    #pragma unroll
    for (int i=0;i<2;i++)
      #pragma unroll
      for (int j=0;j<2;j++)
        #pragma unroll
        for (int k=0;k<10;k++)
          red[(((i*2+j)*10)+k)*64 + lane] = acc[i][j][k];
  }
  __syncthreads();
  if (wid == 0){
    #pragma unroll
    for (int i=0;i<2;i++)
      #pragma unroll
      for (int j=0;j<2;j++)
        #pragma unroll
        for (int k=0;k<10;k++)
          acc[i][j][k] += red[(((i*2+j)*10)+k)*64 + lane];

    float bb = bias[oc];
    float s = 0.f, s2 = 0.f;
    float* op = out + (((size_t)oc*9 + pz)*9 + py)*3*256 + lane*4;
    if (xh == 0){
      float px[5];
      #pragma unroll
      for (int p = 0; p < 5; p++){
        float m = fmaxf(fmaxf(acc[0][0][2*p], acc[0][0][2*p+1]),
                        fmaxf(acc[0][1][2*p], acc[0][1][2*p+1]));
        m = fmaxf(m, fmaxf(fmaxf(acc[1][0][2*p], acc[1][0][2*p+1]),
                           fmaxf(acc[1][1][2*p], acc[1][1][2*p+1])));
        px[p] = m + bb;
        s += px[p]; s2 += px[p]*px[p];
      }
      *(float4*)(op) = make_float4(px[0], px[1], px[2], px[3]);
      op[256] = px[4];
    } else {
      float px[4];
      #pragma unroll
      for (int p = 0; p < 4; p++){   // px = 5+p
        float m = fmaxf(fmaxf(acc[0][0][2*p], acc[0][0][2*p+1]),
                        fmaxf(acc[0][1][2*p], acc[0][1][2*p+1]));
        m = fmaxf(m, fmaxf(fmaxf(acc[1][0][2*p], acc[1][0][2*p+1]),
                           fmaxf(acc[1][1][2*p], acc[1][1][2*p+1])));
        px[p] = m + bb;
        s += px[p]; s2 += px[p]*px[p];
      }
      op[256+1] = px[0]; op[256+2] = px[1]; op[256+3] = px[2]; op[512] = px[3];
    }
    #pragma unroll
    for (int d = 32; d > 0; d >>= 1){ s += __shfl_down(s, d); s2 += __shfl_down(s2, d); }
    if (lane == 0){
      int pi = oc*162 + sp*2 + xh;
      part[(size_t)pi*2] = s; part[(size_t)pi*2+1] = s2;
    }
  }
}

// ============ conv1: 16->32; XCD swizzle; 4 waves = ic-quarters; icl UNROLLED ============
__global__ __launch_bounds__(256) void conv1t_kernel(const float* __restrict__ p0t, // [16][9][9][3][64][4]
                                                     const float* __restrict__ w,
                                                     const float* __restrict__ bias,
                                                     const float* __restrict__ sc,
                                                     const float* __restrict__ sh,
                                                     float* __restrict__ out,   // [32][4][4][64][4]
                                                     float* __restrict__ part)  // [32*16][2]
{
  __shared__ float red[3*32*64];
  int bid = blockIdx.x;                  // 0..511
  int l = (bid & 7)*64 + (bid >> 3);     // 512 = 8*64, sp-major logical
  int oc = l & 31;
  int sp = l >> 5;                       // 0..15
  int pz = sp >> 2, py = sp & 3;
  int tid = threadIdx.x;
  int wid = tid >> 6, lane = tid & 63;

  float acc[2][2][8];
  #pragma unroll
  for (int i=0;i<2;i++)
    #pragma unroll
    for (int j=0;j<2;j++)
      #pragma unroll
      for (int k=0;k<8;k++) acc[i][j][k]=0.f;

  const float* wbp = w + (size_t)oc*16*27;
  #pragma unroll
  for (int icl = 0; icl < 4; icl++){
    int ic = wid*4 + icl;
    float wr[27];
    #pragma unroll
    for (int k = 0; k < 27; k++) wr[k] = wbp[ic*27 + k];
    float s0v = sc[ic], h0v = sh[ic];
    #pragma unroll
    for (int zl = 0; zl < 4; zl++){
      int gz = 2*pz - 1 + zl;            // [-1..8]
      bool vz = ((unsigned)gz < 9u);
      int gzc = vz ? gz : 0;
      #pragma unroll
      for (int yl = 0; yl < 4; yl++){
        int gy = 2*py - 1 + yl;          // [-1..8]
        bool v = vz && ((unsigned)gy < 9u);
        int gyc = ((unsigned)gy < 9u) ? gy : 0;
        const float* rp = p0t + (((size_t)ic*9 + gzc)*9 + gyc)*3*256 + lane*4;
        float4 A0 = *(const float4*)(rp);
        float4 A1 = *(const float4*)(rp + 256);
        float  A2 = rp[512];
        float xv[10];
        xv[0]=0.f;
        xv[1]=leaky(fmaf(A0.x, s0v, h0v)); xv[2]=leaky(fmaf(A0.y, s0v, h0v));
        xv[3]=leaky(fmaf(A0.z, s0v, h0v)); xv[4]=leaky(fmaf(A0.w, s0v, h0v));
        xv[5]=leaky(fmaf(A1.x, s0v, h0v)); xv[6]=leaky(fmaf(A1.y, s0v, h0v));
        xv[7]=leaky(fmaf(A1.z, s0v, h0v)); xv[8]=leaky(fmaf(A1.w, s0v, h0v));
        xv[9]=leaky(fmaf(A2,   s0v, h0v));
        #pragma unroll
        for (int czl = 0; czl < 2; czl++){
          const int dz = zl - czl; if (dz < 0 || dz > 2) continue;
          #pragma unroll
          for (int cyl = 0; cyl < 2; cyl++){
            const int dy = yl - cyl; if (dy < 0 || dy > 2) continue;
            const int wb = dz*9 + dy*3;
            const float w0 = v ? wr[wb]   : 0.f;
            const float w1 = v ? wr[wb+1] : 0.f;
            const float w2 = v ? wr[wb+2] : 0.f;
            #pragma unroll
            for (int cx = 0; cx < 8; cx++){
              float a = acc[czl][cyl][cx];
              a = fmaf(xv[cx],   w0, a);
              a = fmaf(xv[cx+1], w1, a);
              a = fmaf(xv[cx+2], w2, a);
              acc[czl][cyl][cx] = a;
            }
          }
        }
      }
    }
  }
  if (wid > 0){
    #pragma unroll
    for (int i=0;i<2;i++)
      #pragma unroll
      for (int j=0;j<2;j++)
        #pragma unroll
        for (int k=0;k<8;k++)
          red[(((wid-1)*32) + (i*2+j)*8 + k)*64 + lane] = acc[i][j][k];
  }
  __syncthreads();
  if (wid == 0){
    #pragma unroll
    for (int q = 0; q < 3; q++)
      #pragma unroll
      for (int i=0;i<2;i++)
        #pragma unroll
        for (int j=0;j<2;j++)
          #pragma unroll
          for (int k=0;k<8;k++)
            acc[i][j][k] += red[((q*32) + (i*2+j)*8 + k)*64 + lane];

    float bb = bias[oc];
    float px[4];
    float s = 0.f, s2 = 0.f;
    #pragma unroll
    for (int p = 0; p < 4; p++){
      float m = fmaxf(fmaxf(acc[0][0][2*p], acc[0][0][2*p+1]),
                      fmaxf(acc[0][1][2*p], acc[0][1][2*p+1]));
      m = fmaxf(m, fmaxf(fmaxf(acc[1][0][2*p], acc[1][0][2*p+1]),
                         fmaxf(acc[1][1][2*p], acc[1][1][2*p+1])));
      px[p] = m + bb;
      s += px[p]; s2 += px[p]*px[p];
    }
    *(float4*)(out + (((size_t)oc*4 + pz)*4 + py)*256 + lane*4) =
        make_float4(px[0], px[1], px[2], px[3]);
    #pragma unroll
    for (int d = 32; d > 0; d >>= 1){ s += __shfl_down(s, d); s2 += __shfl_down(s2, d); }
    if (lane == 0){
      int pi = oc*16 + sp;
      part[(size_t)pi*2] = s; part[(size_t)pi*2+1] = s2;
    }
  }
}

// ============ conv2: 32->64; XCD swizzle; 8 waves = Px × ic-quarter; icl UNROLLED +
// clamped rows + uniform weight-zeroing ============
__global__ __launch_bounds__(512) void conv2t_kernel(const float* __restrict__ p1t, // [32][4][4][64][4]
                                                     const float* __restrict__ w,
                                                     const float* __restrict__ bias,
                                                     const float* __restrict__ sc,
                                                     const float* __restrict__ sh,
                                                     float* __restrict__ out)  // [64*8][64] = p2t
{
  __shared__ float red[6*8*64];          // 12 KB: icq=1..3 partials for each Px
  int bid = blockIdx.x;                  // 0..255
  int l = (bid & 7)*32 + (bid >> 3);     // 256 = 8*32, q-major logical
  int oc = l & 63;
  int q  = l >> 6;                       // 0..3
  int Pz = q >> 1, Py = q & 1;
  int tid = threadIdx.x;
  int wid = tid >> 6, lane = tid & 63;
  int Px = wid >> 2, icq = wid & 3;

  float acc[2][2][2];
  #pragma unroll
  for (int i=0;i<2;i++)
    #pragma unroll
    for (int j=0;j<2;j++)
      #pragma unroll
      for (int k=0;k<2;k++) acc[i][j][k]=0.f;

  const float* wbp = w + (size_t)oc*32*27;
  #pragma unroll
  for (int icl = 0; icl < 8; icl++){
    int ic = icq*8 + icl;
    float wr[27];
    #pragma unroll
    for (int k = 0; k < 27; k++) wr[k] = wbp[ic*27 + k];
    float s1v = sc[ic], h1v = sh[ic];
    #pragma unroll
    for (int zl = 0; zl < 4; zl++){
      int gz = 2*Pz - 1 + zl;            // [-1..4]
      bool vz = ((unsigned)gz < 4u);
      int gzc = vz ? gz : (gz < 0 ? 0 : 3);
      #pragma unroll
      for (int yl = 0; yl < 4; yl++){
        int gy = 2*Py - 1 + yl;          // [-1..4]
        bool v = vz && ((unsigned)gy < 4u);
        int gyc = ((unsigned)gy < 4u) ? gy : (gy < 0 ? 0 : 3);
        float4 f = *(const float4*)(p1t + (((size_t)ic*4 + gzc)*4 + gyc)*256 + lane*4);
        float b0 = leaky(fmaf(f.x, s1v, h1v));
        float b1 = leaky(fmaf(f.y, s1v, h1v));
        float b2 = leaky(fmaf(f.z, s1v, h1v));
        float b3 = leaky(fmaf(f.w, s1v, h1v));
        float win[4];
        if (Px == 0){ win[0]=0.f; win[1]=b0; win[2]=b1; win[3]=b2; }
        else        { win[0]=b1;  win[1]=b2; win[2]=b3; win[3]=0.f; }
        #pragma unroll
        for (int czl = 0; czl < 2; czl++){
          const int dz = zl - czl; if (dz < 0 || dz > 2) continue;
          #pragma unroll
          for (int cyl = 0; cyl < 2; cyl++){
            const int dy = yl - cyl; if (dy < 0 || dy > 2) continue;
            const int wb = dz*9 + dy*3;
            const float w0 = v ? wr[wb]   : 0.f;   // uniform select (SALU)
            const float w1 = v ? wr[wb+1] : 0.f;
            const float w2 = v ? wr[wb+2] : 0.f;
            #pragma unroll
            for (int cxl = 0; cxl < 2; cxl++){
              float a = acc[czl][cyl][cxl];
              a = fmaf(win[cxl],   w0, a);
              a = fmaf(win[cxl+1], w1, a);
              a = fmaf(win[cxl+2], w2, a);
              acc[czl][cyl][cxl] = a;
            }
          }
        }
      }
    }
  }
  if (icq > 0){
    #pragma unroll
    for (int i=0;i<2;i++)
      #pragma unroll
      for (int j=0;j<2;j++)
        #pragma unroll
        for (int k=0;k<2;k++)
          red[(((Px*3 + icq-1)*8) + (i*2+j)*2 + k)*64 + lane] = acc[i][j][k];
  }
  __syncthreads();
  if (icq == 0){
    #pragma unroll
    for (int qq = 0; qq < 3; qq++)
      #pragma unroll
      for (int i=0;i<2;i++)
        #pragma unroll
        for (int j=0;j<2;j++)
          #pragma unroll
          for (int k=0;k<2;k++)
            acc[i][j][k] += red[(((Px*3 + qq)*8) + (i*2+j)*2 + k)*64 + lane];

    float bb = bias[oc];
    float m = fmaxf(fmaxf(acc[0][0][0], acc[0][0][1]), fmaxf(acc[0][1][0], acc[0][1][1]));
    m = fmaxf(m, fmaxf(fmaxf(acc[1][0][0], acc[1][0][1]), fmaxf(acc[1][1][0], acc[1][1][1])));
    out[((size_t)oc*8 + Pz*4 + Py*2 + Px)*64 + lane] = m + bb;
  }
}

// ---------------- stats finalize: per-channel partials -> scale/shift ----------------
template<int C, int N>
__global__ __launch_bounds__(256) void stats_final(const float* __restrict__ part,
                                                   float* __restrict__ scale,
                                                   float* __restrict__ shift,
                                                   const float* __restrict__ g,
                                                   const float* __restrict__ bb,
                                                   float n)
{
  int c = blockIdx.x;
  float s = 0.f, s2 = 0.f;
  for (int i = threadIdx.x; i < N; i += 256){
    s  += part[(size_t)(c*N + i)*2];
    s2 += part[(size_t)(c*N + i)*2 + 1];
  }
  #pragma unroll
  for (int d = 32; d > 0; d >>= 1){ s += __shfl_down(s, d); s2 += __shfl_down(s2, d); }
  __shared__ float rs[4], rq[4];
  int lane = threadIdx.x & 63, wid = threadIdx.x >> 6;
  if (lane == 0){ rs[wid] = s; rq[wid] = s2; }
  __syncthreads();
  if (threadIdx.x == 0){
    float ts = rs[0]+rs[1]+rs[2]+rs[3];
    float tq = rq[0]+rq[1]+rq[2]+rq[3];
    float m = ts / n;
    float var = tq / n - m*m;
    float is = rsqrtf(var + 1e-5f);
    float scv = is * g[c];
    scale[c] = scv;
    shift[c] = bb[c] - m * scv;
  }
}

// ---------------- BN2 stats on transposed p2t: one wave per channel ----------------
__global__ __launch_bounds__(256) void bn2t_kernel(const float* __restrict__ p2t,
                                                   const float* __restrict__ g,
                                                   const float* __restrict__ bb,
                                                   float* __restrict__ scale,
                                                   float* __restrict__ shift)
{
  int gt = blockIdx.x*256 + threadIdx.x;
  int c = gt >> 6, lane = gt & 63;
  if (c >= 64) return;
  const float* p = p2t + (size_t)c*512;
  float s = 0.f, s2 = 0.f;
  #pragma unroll
  for (int i = 0; i < 8; i++){ float v = p[i*64 + lane]; s += v; s2 += v*v; }
  #pragma unroll
  for (int d = 32; d > 0; d >>= 1){ s += __shfl_down(s, d); s2 += __shfl_down(s2, d); }
  if (lane == 0){
    float m = s * (1.f/512.f);
    float var = s2 * (1.f/512.f) - m*m;
    float scv = rsqrtf(var + 1e-5f) * g[c];
    scale[c] = scv;
    shift[c] = bb[c] - m*scv;
  }
}

// ---------------- fc0: block per feature, 4 waves K-split + BN2-on-load + batch-BN3 ----------------
__global__ __launch_bounds__(256) void fc0bn_kernel(const float* __restrict__ p2t,
                                                    const float* __restrict__ W,
                                                    const float* __restrict__ bias,
                                                    const float* __restrict__ sc,
                                                    const float* __restrict__ sh,
                                                    const float* __restrict__ g,
                                                    const float* __restrict__ bb,
                                                    float* __restrict__ y0t)
{
  __shared__ float red[3][64];
  int f = blockIdx.x;                    // 0..511
  int wid = threadIdx.x >> 6, r = threadIdx.x & 63;
  const float* wr = W + (size_t)f*512;
  float a = 0.f;
  for (int c = wid*16; c < wid*16 + 16; c++){
    float s = sc[c], h = sh[c];
    #pragma unroll
    for (int jj = 0; jj < 8; jj++){
      int i = c*8 + jj;
      float xv = leaky(fmaf(p2t[(size_t)i*64 + r], s, h));
      a = fmaf(xv, wr[i], a);
    }
  }
  if (wid > 0) red[wid-1][r] = a;
  __syncthreads();
  if (wid == 0){
    a += red[0][r] + red[1][r] + red[2][r] + bias[f];
    float s1 = a, s2 = a*a;
    #pragma unroll
    for (int d = 32; d > 0; d >>= 1){ s1 += __shfl_down(s1, d); s2 += __shfl_down(s2, d); }
    s1 = __shfl(s1, 0); s2 = __shfl(s2, 0);
    float m = s1 * (1.f/64.f);
    float var = s2 * (1.f/64.f) - m*m;
    float is = rsqrtf(var + 1e-5f);
    y0t[(size_t)f*64 + r] = leaky((a - m) * is * g[f] + bb[f]);
  }
}

// ---------------- fc1: block per feature, 8 waves K-split + batch-BN4 ----------------
__global__ __launch_bounds__(512) void fc1bn_kernel(const float* __restrict__ y0t,
                                                    const float* __restrict__ W,
                                                    const float* __restrict__ bias,
                                                    const float* __restrict__ g,
                                                    const float* __restrict__ bb,
                                                    float* __restrict__ y1t)
{
  __shared__ float red[7][64];
  int f = blockIdx.x;                    // 0..255
  int wid = threadIdx.x >> 6, r = threadIdx.x & 63;
  const float* wr = W + (size_t)f*512;
  float a = 0.f;
  #pragma unroll 8
  for (int i = wid*64; i < wid*64 + 64; i++)
    a = fmaf(y0t[(size_t)i*64 + r], wr[i], a);
  if (wid > 0) red[wid-1][r] = a;
  __syncthreads();
  if (wid == 0){
    #pragma unroll
    for (int q = 0; q < 7; q++) a += red[q][r];
    a += bias[f];
    float s1 = a, s2 = a*a;
    #pragma unroll
    for (int d = 32; d > 0; d >>= 1){ s1 += __shfl_down(s1, d); s2 += __shfl_down(s2, d); }
    s1 = __shfl(s1, 0); s2 = __shfl(s2, 0);
    float m = s1 * (1.f/64.f);
    float var = s2 * (1.f/64.f) - m*m;
    float is = rsqrtf(var + 1e-5f);
    y1t[(size_t)f*64 + r] = leaky((a - m) * is * g[f] + bb[f]);
  }
}

// ---------------- fc2: block per feature, 4 waves K-split + leaky ----------------
__global__ __launch_bounds__(256) void fc2_kernel(const float* __restrict__ y1t,
                                                  const float* __restrict__ W,
                                                  const float* __restrict__ bias,
                                                  float* __restrict__ y2t)
{
  __shared__ float red[3][64];
  int f = blockIdx.x;                    // 0..99
  int wid = threadIdx.x >> 6, r = threadIdx.x & 63;
  const float* wr = W + (size_t)f*256;
  float a = 0.f;
  #pragma unroll 8
  for (int i = wid*64; i < wid*64 + 64; i++)
    a = fmaf(y1t[(size_t)i*64 + r], wr[i], a);
  if (wid > 0) red[wid-1][r] = a;
  __syncthreads();
  if (wid == 0){
    a += red[0][r] + red[1][r] + red[2][r];
    y2t[(size_t)f*64 + r] = leaky(a + bias[f]);
  }
}

// ---------------- head (100->20), wave/output ----------------
__global__ __launch_bounds__(256) void head_kernel(const float* __restrict__ y2t,
                                                   const float* __restrict__ W,
                                                   const float* __restrict__ bias,
                                                   float* __restrict__ out)
{
  int gt = blockIdx.x*256 + threadIdx.x;
  int oo = gt >> 6, r = gt & 63;
  if (oo >= 20) return;
  const float* wr = W + (size_t)oo*100;
  float a = 0.f;
  #pragma unroll 4
  for (int i = 0; i < 100; i++)
    a = fmaf(y2t[(size_t)i*64 + r], wr[i], a);
  out[(size_t)r*20 + oo] = a + bias[oo];
}

extern "C" void kernel_launch(void* const* d_in, const int* in_sizes, int n_in,
                              void* d_out, int out_size, void* d_ws, size_t ws_size,
                              hipStream_t stream)
{
  const float* x   = (const float*)d_in[0];
  const float* cw0 = (const float*)d_in[2];  const float* cb0 = (const float*)d_in[3];
  const float* g0  = (const float*)d_in[4];  const float* bb0 = (const float*)d_in[5];
  const float* cw1 = (const float*)d_in[6];  const float* cb1 = (const float*)d_in[7];
  const float* g1  = (const float*)d_in[8];  const float* bb1 = (const float*)d_in[9];
  const float* cw2 = (const float*)d_in[10]; const float* cb2 = (const float*)d_in[11];
  const float* g2  = (const float*)d_in[12]; const float* bb2 = (const float*)d_in[13];
  const float* mw0 = (const float*)d_in[14]; const float* mb0 = (const float*)d_in[15];
  const float* g3  = (const float*)d_in[16]; const float* bb3 = (const float*)d_in[17];
  const float* mw1 = (const float*)d_in[18]; const float* mb1 = (const float*)d_in[19];
  const float* g4  = (const float*)d_in[20]; const float* bb4 = (const float*)d_in[21];
  const float* mw2 = (const float*)d_in[22]; const float* mb2 = (const float*)d_in[23];
  const float* hw  = (const float*)d_in[24]; const float* hb  = (const float*)d_in[25];

  float* ws     = (float*)d_ws;
  // Region A (2488320): tab during blur (first 2097152), then ft [6][18][18][5][64][4]
  float* tab    = ws;
  float* ft     = ws;
  int*   dst    = (int*)(ws + 2097152);  // tail of A, dead before ft is written
  int*   sstart = dst + 32768;
  int*   scount = sstart + 384;
  // Region B (2239488): fields during blur, then p0t [16][9][9][3][64][4] (995328)
  float* fields = ws + 2488320;
  float* p0t    = fields;
  float* rest   = fields + 2239488;
  float* p1t    = rest;                  // 131072  [32][4][4][64][4]
  float* p2t    = p1t + 131072;          // 32768   [512][64]
  float* y0t    = p2t + 32768;           // 32768
  float* y1t    = y0t + 32768;           // 16384
  float* y2t    = y1t + 16384;           // 6400
  float* part   = y2t + 6400;            // 6144 (max 16*162*2 = 5184)
  float* sc0    = part + 6144;           // 16
  float* sh0    = sc0 + 16;
  float* sc1    = sh0 + 16;              // 32
  float* sh1    = sc1 + 32;
  float* sc2    = sh1 + 32;              // 64
  float* sh2    = sc2 + 64;
  float* outp   = (float*)d_out;

  atom_sort<<<64, 64, 0, stream>>>(x, dst, sstart, scount);
  blur_prep<<<128, 256, 0, stream>>>(x, dst, tab);
  blur_accum<<<768, 192, 0, stream>>>(tab, sstart, scount, fields);
  transpose_fields<<<216, 256, 0, stream>>>(fields, ft);

  conv0t_kernel<<<2592, 128, 0, stream>>>(ft, cw0, cb0, p0t, part);
  stats_final<16,162><<<16, 256, 0, stream>>>(part, sc0, sh0, g0, bb0, 64.f*729.f);

  conv1t_kernel<<<512, 256, 0, stream>>>(p0t, cw1, cb1, sc0, sh0, p1t, part);
  stats_final<32,16><<<32, 256, 0, stream>>>(part, sc1, sh1, g1, bb1, 64.f*64.f);

  conv2t_kernel<<<256, 512, 0, stream>>>(p1t, cw2, cb2, sc1, sh1, p2t);
  bn2t_kernel<<<16, 256, 0, stream>>>(p2t, g2, bb2, sc2, sh2);

  fc0bn_kernel<<<512, 256, 0, stream>>>(p2t, mw0, mb0, sc2, sh2, g3, bb3, y0t);
  fc1bn_kernel<<<256, 512, 0, stream>>>(y0t, mw1, mb1, g4, bb4, y1t);
  fc2_kernel<<<100, 256, 0, stream>>>(y1t, mw2, mb2, y2t);
  head_kernel<<<5, 256, 0, stream>>>(y2t, hw, hb, outp);
}

// Round 19
// 164.642 us; speedup vs baseline: 1.0440x; 1.0440x over previous
//
#include <hip/hip_runtime.h>
#include <math.h>

#define BATCH 64
#define APB 512
#define NA 6
#define NG 5832  // 18^3

__device__ __forceinline__ float leaky(float v){ return v >= 0.f ? v : 0.01f*v; }

// ============ atom sort: deterministic counting sort by (batch, type) ============
__global__ __launch_bounds__(64) void atom_sort(const float* __restrict__ x,
                                                int* __restrict__ dst,
                                                int* __restrict__ seg_start,
                                                int* __restrict__ seg_count)
{
  int batch = blockIdx.x;
  int lane  = threadIdx.x;
  int tyc[8];
  int cnt[NA];
  #pragma unroll
  for (int t = 0; t < NA; t++) cnt[t] = 0;
  #pragma unroll
  for (int c = 0; c < 8; c++){
    int a = batch*APB + c*64 + lane;
    int ty = (int)x[(size_t)a*5 + 1];
    tyc[c] = ty;
    #pragma unroll
    for (int t = 0; t < NA; t++){
      unsigned long long m = __ballot(ty == t);
      cnt[t] += __popcll(m);
    }
  }
  int pre[NA+1];
  pre[0] = 0;
  #pragma unroll
  for (int t = 0; t < NA; t++) pre[t+1] = pre[t] + cnt[t];
  if (lane < NA){
    seg_start[batch*NA + lane] = batch*APB + pre[lane];
    seg_count[batch*NA + lane] = cnt[lane];
  }
  int run[NA];
  #pragma unroll
  for (int t = 0; t < NA; t++) run[t] = pre[t];
  unsigned long long below = (lane == 0) ? 0ull : ((~0ull) >> (64 - lane));
  #pragma unroll
  for (int c = 0; c < 8; c++){
    int a = batch*APB + c*64 + lane;
    int ty = tyc[c];
    int rank = 0;
    #pragma unroll
    for (int t = 0; t < NA; t++){
      unsigned long long m = __ballot(ty == t);
      if (ty == t) rank = run[t] + __popcll(m & below);
      run[t] += __popcll(m);
    }
    dst[a] = batch*APB + rank;
  }
}

// ============ blur phase 1: per-atom separable 1-D tables (sorted rows) ============
__global__ __launch_bounds__(256) void blur_prep(const float* __restrict__ x,
                                                 const int* __restrict__ dst,
                                                 float* __restrict__ tab)
{
  int a = blockIdx.x*256 + threadIdx.x;
  if (a >= BATCH*APB) return;
  const float* row = x + (size_t)a*5;
  float p0 = row[2], p1 = row[3], p2 = row[4];
  float e[54];
  float s0 = 0.f, s1 = 0.f, s2 = 0.f;
  #pragma unroll
  for (int i = 0; i < 18; i++){
    float g = (float)i - 8.5f;
    float d0 = p0 - g, d1 = p1 - g, d2 = p2 - g;
    float v0 = __expf(d0*d0 * (-1.f/0.72f));
    float v1 = __expf(d1*d1 * (-1.f/0.72f));
    float v2 = __expf(d2*d2 * (-1.f/0.72f));
    e[i] = v0; e[18+i] = v1; e[36+i] = v2;
    s0 += v0; s1 += v1; s2 += v2;
  }
  float inv = 1.f / (s0*s1*s2 + 1e-6f);
  float* tp = tab + (size_t)dst[a]*64;
  #pragma unroll
  for (int i = 0; i < 18; i++) tp[i] = e[i]*inv;
  tp[18] = 0.f; tp[19] = 0.f;
  #pragma unroll
  for (int i = 0; i < 18; i++) tp[20+i] = e[18+i];
  #pragma unroll
  for (int i = 0; i < 18; i++) tp[40+i] = e[36+i];
}

// ============ blur phase 2: branch-free streaming outer-product ============
__global__ __launch_bounds__(192) void blur_accum(const float* __restrict__ tab,
                                                  const int* __restrict__ seg_start,
                                                  const int* __restrict__ seg_count,
                                                  float* __restrict__ fields)
{
  int bid  = blockIdx.x;
  int seg  = bid >> 1;
  int half = bid & 1;
  int tid = threadIdx.x;
  bool act = tid < 162;
  int ix = half*9 + tid/18;
  int iy = tid % 18;

  float acc[18];
  #pragma unroll
  for (int k = 0; k < 18; k++) acc[k] = 0.f;

  int start = seg_start[seg], count = seg_count[seg];
  const float* tb = tab + (size_t)start*64;

  int j = 0;
  for (; j + 3 < count; j += 4){
    const float* t0 = tb + (size_t)(j+0)*64;
    const float* t1 = tb + (size_t)(j+1)*64;
    const float* t2 = tb + (size_t)(j+2)*64;
    const float* t3 = tb + (size_t)(j+3)*64;
    float e0 = t0[ix]*t0[20+iy];
    float e1 = t1[ix]*t1[20+iy];
    float e2 = t2[ix]*t2[20+iy];
    float e3 = t3[ix]*t3[20+iy];
    #pragma unroll
    for (int k = 0; k < 18; k++){
      float a = acc[k];
      a = fmaf(e0, t0[40+k], a);
      a = fmaf(e1, t1[40+k], a);
      a = fmaf(e2, t2[40+k], a);
      a = fmaf(e3, t3[40+k], a);
      acc[k] = a;
    }
  }
  for (; j < count; j++){
    const float* t0 = tb + (size_t)j*64;
    float e0 = t0[ix]*t0[20+iy];
    #pragma unroll
    for (int k = 0; k < 18; k++)
      acc[k] = fmaf(e0, t0[40+k], acc[k]);
  }
  if (act){
    float* fo = fields + (size_t)seg*NG + (size_t)(ix*18 + iy)*18;
    #pragma unroll
    for (int k = 0; k < 18; k++) fo[k] = acc[k];
  }
}

// ============ transpose fields[b*6+t][z*324+y*18+x] -> ft[t][z][y][xq][b][4xr] ============
__global__ __launch_bounds__(256) void transpose_fields(const float* __restrict__ fields,
                                                        float* __restrict__ ft)
{
  __shared__ float tile[64*162];
  int bid = blockIdx.x;           // t*36 + gz*2 + gyh
  int t = bid / 36; int r = bid - t*36;
  int gz = r >> 1, gyh = r & 1;
  int tid = threadIdx.x;

  for (int idx = tid; idx < 64*162; idx += 256){
    int b = idx / 162; int c = idx - b*162;
    tile[idx] = fields[(size_t)(b*NA + t)*NG + gz*324 + gyh*162 + c];
  }
  __syncthreads();
  for (int idx = tid; idx < 9*5*64; idx += 256){
    int r2 = idx >> 6; int b = idx & 63;
    int gy = r2 / 5, xq = r2 - gy*5;
    int x0 = xq*4;
    const float* tp = &tile[b*162 + gy*18];
    float4 v;
    v.x = (x0   < 18) ? tp[x0]   : 0.f;
    v.y = (x0+1 < 18) ? tp[x0+1] : 0.f;
    v.z = (x0+2 < 18) ? tp[x0+2] : 0.f;
    v.w = (x0+3 < 18) ? tp[x0+3] : 0.f;
    *(float4*)(ft + ((((size_t)t*18 + gz)*18 + (gyh*9+gy))*5 + xq)*256 + b*4) = v;
  }
}

// ============ conv0: 6->16; single wave per (oc,sp,xh); xh branch hoisted; straight-line ============
__global__ __launch_bounds__(64) void conv0t_kernel(const float* __restrict__ ft,
                                                    const float* __restrict__ w,
                                                    const float* __restrict__ bias,
                                                    float* __restrict__ out,   // [16][9][9][3xq][64][4]
                                                    float* __restrict__ part)  // [16*162][2]
{
  int bid = blockIdx.x;                  // 0..2591
  int l = (bid & 7)*324 + (bid >> 3);    // XCD-aware bijection (2592 = 8*324)
  int oc = l & 15, xh = (l >> 4) & 1;
  int sp = l >> 5;                       // 0..80
  int pz = sp / 9, py = sp - pz*9;
  int lane = threadIdx.x;

  float acc[2][2][10];
  #pragma unroll
  for (int i=0;i<2;i++)
    #pragma unroll
    for (int j=0;j<2;j++)
      #pragma unroll
      for (int k=0;k<10;k++) acc[i][j][k]=0.f;

  float bb = bias[oc];
  float s = 0.f, s2 = 0.f;
  float* op = out + (((size_t)oc*9 + pz)*9 + py)*3*256 + lane*4;

  if (xh == 0){
    #pragma unroll
    for (int ic = 0; ic < 6; ic++){
      float wr[27];
      #pragma unroll
      for (int k = 0; k < 27; k++) wr[k] = w[(oc*6+ic)*27 + k];
      #pragma unroll
      for (int zl = 0; zl < 4; zl++){
        int gz = 2*pz - 1 + zl;
        bool vz = ((unsigned)gz < 18u);
        int gzc = vz ? gz : (gz < 0 ? 0 : 17);
        #pragma unroll
        for (int yl = 0; yl < 4; yl++){
          int gy = 2*py - 1 + yl;
          bool v = vz && ((unsigned)gy < 18u);
          int gyc = ((unsigned)gy < 18u) ? gy : (gy < 0 ? 0 : 17);
          const float* rp = ft + (((size_t)ic*18 + gzc)*18 + gyc)*5*256 + lane*4;
          float4 A0 = *(const float4*)(rp);
          float4 A1 = *(const float4*)(rp + 256);
          float4 A2 = *(const float4*)(rp + 512);
          float xv[13];
          xv[0] = 0.f;
          *(float4*)&xv[1] = A0; *(float4*)&xv[5] = A1; *(float4*)&xv[9] = A2;
          #pragma unroll
          for (int czl = 0; czl < 2; czl++){
            const int dz = zl - czl; if (dz < 0 || dz > 2) continue;
            #pragma unroll
            for (int cyl = 0; cyl < 2; cyl++){
              const int dy = yl - cyl; if (dy < 0 || dy > 2) continue;
              const int wb = dz*9 + dy*3;
              const float w0 = v ? wr[wb]   : 0.f;   // uniform select (SALU)
              const float w1 = v ? wr[wb+1] : 0.f;
              const float w2 = v ? wr[wb+2] : 0.f;
              #pragma unroll
              for (int cx = 0; cx < 10; cx++){
                float a = acc[czl][cyl][cx];
                a = fmaf(xv[cx],   w0, a);
                a = fmaf(xv[cx+1], w1, a);
                a = fmaf(xv[cx+2], w2, a);
                acc[czl][cyl][cx] = a;
              }
            }
          }
        }
      }
    }
    float px[5];
    #pragma unroll
    for (int p = 0; p < 5; p++){
      float m = fmaxf(fmaxf(acc[0][0][2*p], acc[0][0][2*p+1]),
                      fmaxf(acc[0][1][2*p], acc[0][1][2*p+1]));
      m = fmaxf(m, fmaxf(fmaxf(acc[1][0][2*p], acc[1][0][2*p+1]),
                         fmaxf(acc[1][1][2*p], acc[1][1][2*p+1])));
      px[p] = m + bb;
      s += px[p]; s2 += px[p]*px[p];
    }
    *(float4*)(op) = make_float4(px[0], px[1], px[2], px[3]);
    op[256] = px[4];
  } else {
    #pragma unroll
    for (int ic = 0; ic < 6; ic++){
      float wr[27];
      #pragma unroll
      for (int k = 0; k < 27; k++) wr[k] = w[(oc*6+ic)*27 + k];
      #pragma unroll
      for (int zl = 0; zl < 4; zl++){
        int gz = 2*pz - 1 + zl;
        bool vz = ((unsigned)gz < 18u);
        int gzc = vz ? gz : (gz < 0 ? 0 : 17);
        #pragma unroll
        for (int yl = 0; yl < 4; yl++){
          int gy = 2*py - 1 + yl;
          bool v = vz && ((unsigned)gy < 18u);
          int gyc = ((unsigned)gy < 18u) ? gy : (gy < 0 ? 0 : 17);
          const float* rp = ft + (((size_t)ic*18 + gzc)*18 + gyc)*5*256 + lane*4;
          float4 A2 = *(const float4*)(rp + 512);
          float4 A3 = *(const float4*)(rp + 768);
          float4 A4 = *(const float4*)(rp + 1024);
          float win[12];                            // win[j] = p(9+j); p18,p19 stored zero
          *(float4*)&win[0] = A2; *(float4*)&win[4] = A3; *(float4*)&win[8] = A4;
          #pragma unroll
          for (int czl = 0; czl < 2; czl++){
            const int dz = zl - czl; if (dz < 0 || dz > 2) continue;
            #pragma unroll
            for (int cyl = 0; cyl < 2; cyl++){
              const int dy = yl - cyl; if (dy < 0 || dy > 2) continue;
              const int wb = dz*9 + dy*3;
              const float w0 = v ? wr[wb]   : 0.f;
              const float w1 = v ? wr[wb+1] : 0.f;
              const float w2 = v ? wr[wb+2] : 0.f;
              #pragma unroll
              for (int cl = 0; cl < 8; cl++){       // cx = 10+cl
                float a = acc[czl][cyl][cl];
                a = fmaf(win[cl+1], w0, a);
                a = fmaf(win[cl+2], w1, a);
                a = fmaf(win[cl+3], w2, a);
                acc[czl][cyl][cl] = a;
              }
            }
          }
        }
      }
    }
    float px[4];
    #pragma unroll
    for (int p = 0; p < 4; p++){   // px = 5+p
      float m = fmaxf(fmaxf(acc[0][0][2*p], acc[0][0][2*p+1]),
                      fmaxf(acc[0][1][2*p], acc[0][1][2*p+1]));
      m = fmaxf(m, fmaxf(fmaxf(acc[1][0][2*p], acc[1][0][2*p+1]),
                         fmaxf(acc[1][1][2*p], acc[1][1][2*p+1])));
      px[p] = m + bb;
      s += px[p]; s2 += px[p]*px[p];
    }
    op[256+1] = px[0]; op[256+2] = px[1]; op[256+3] = px[2]; op[512] = px[3];
  }
  #pragma unroll
  for (int d = 32; d > 0; d >>= 1){ s += __shfl_down(s, d); s2 += __shfl_down(s2, d); }
  if (lane == 0){
    int pi = oc*162 + sp*2 + xh;
    part[(size_t)pi*2] = s; part[(size_t)pi*2+1] = s2;
  }
}

// ============ conv1: 16->32; XCD swizzle; 4 waves = ic-quarters; icl UNROLLED ============
__global__ __launch_bounds__(256) void conv1t_kernel(const float* __restrict__ p0t, // [16][9][9][3][64][4]
                                                     const float* __restrict__ w,
                                                     const float* __restrict__ bias,
                                                     const float* __restrict__ sc,
                                                     const float* __restrict__ sh,
                                                     float* __restrict__ out,   // [32][4][4][64][4]
                                                     float* __restrict__ part)  // [32*16][2]
{
  __shared__ float red[3*32*64];
  int bid = blockIdx.x;                  // 0..511
  int l = (bid & 7)*64 + (bid >> 3);     // 512 = 8*64, sp-major logical
  int oc = l & 31;
  int sp = l >> 5;                       // 0..15
  int pz = sp >> 2, py = sp & 3;
  int tid = threadIdx.x;
  int wid = tid >> 6, lane = tid & 63;

  float acc[2][2][8];
  #pragma unroll
  for (int i=0;i<2;i++)
    #pragma unroll
    for (int j=0;j<2;j++)
      #pragma unroll
      for (int k=0;k<8;k++) acc[i][j][k]=0.f;

  const float* wbp = w + (size_t)oc*16*27;
  #pragma unroll
  for (int icl = 0; icl < 4; icl++){
    int ic = wid*4 + icl;
    float wr[27];
    #pragma unroll
    for (int k = 0; k < 27; k++) wr[k] = wbp[ic*27 + k];
    float s0v = sc[ic], h0v = sh[ic];
    #pragma unroll
    for (int zl = 0; zl < 4; zl++){
      int gz = 2*pz - 1 + zl;            // [-1..8]
      bool vz = ((unsigned)gz < 9u);
      int gzc = vz ? gz : 0;
      #pragma unroll
      for (int yl = 0; yl < 4; yl++){
        int gy = 2*py - 1 + yl;          // [-1..8]
        bool v = vz && ((unsigned)gy < 9u);
        int gyc = ((unsigned)gy < 9u) ? gy : 0;
        const float* rp = p0t + (((size_t)ic*9 + gzc)*9 + gyc)*3*256 + lane*4;
        float4 A0 = *(const float4*)(rp);
        float4 A1 = *(const float4*)(rp + 256);
        float  A2 = rp[512];
        float xv[10];
        xv[0]=0.f;
        xv[1]=leaky(fmaf(A0.x, s0v, h0v)); xv[2]=leaky(fmaf(A0.y, s0v, h0v));
        xv[3]=leaky(fmaf(A0.z, s0v, h0v)); xv[4]=leaky(fmaf(A0.w, s0v, h0v));
        xv[5]=leaky(fmaf(A1.x, s0v, h0v)); xv[6]=leaky(fmaf(A1.y, s0v, h0v));
        xv[7]=leaky(fmaf(A1.z, s0v, h0v)); xv[8]=leaky(fmaf(A1.w, s0v, h0v));
        xv[9]=leaky(fmaf(A2,   s0v, h0v));
        #pragma unroll
        for (int czl = 0; czl < 2; czl++){
          const int dz = zl - czl; if (dz < 0 || dz > 2) continue;
          #pragma unroll
          for (int cyl = 0; cyl < 2; cyl++){
            const int dy = yl - cyl; if (dy < 0 || dy > 2) continue;
            const int wb = dz*9 + dy*3;
            const float w0 = v ? wr[wb]   : 0.f;
            const float w1 = v ? wr[wb+1] : 0.f;
            const float w2 = v ? wr[wb+2] : 0.f;
            #pragma unroll
            for (int cx = 0; cx < 8; cx++){
              float a = acc[czl][cyl][cx];
              a = fmaf(xv[cx],   w0, a);
              a = fmaf(xv[cx+1], w1, a);
              a = fmaf(xv[cx+2], w2, a);
              acc[czl][cyl][cx] = a;
            }
          }
        }
      }
    }
  }
  if (wid > 0){
    #pragma unroll
    for (int i=0;i<2;i++)
      #pragma unroll
      for (int j=0;j<2;j++)
        #pragma unroll
        for (int k=0;k<8;k++)
          red[(((wid-1)*32) + (i*2+j)*8 + k)*64 + lane] = acc[i][j][k];
  }
  __syncthreads();
  if (wid == 0){
    #pragma unroll
    for (int q = 0; q < 3; q++)
      #pragma unroll
      for (int i=0;i<2;i++)
        #pragma unroll
        for (int j=0;j<2;j++)
          #pragma unroll
          for (int k=0;k<8;k++)
            acc[i][j][k] += red[((q*32) + (i*2+j)*8 + k)*64 + lane];

    float bb = bias[oc];
    float px[4];
    float s = 0.f, s2 = 0.f;
    #pragma unroll
    for (int p = 0; p < 4; p++){
      float m = fmaxf(fmaxf(acc[0][0][2*p], acc[0][0][2*p+1]),
                      fmaxf(acc[0][1][2*p], acc[0][1][2*p+1]));
      m = fmaxf(m, fmaxf(fmaxf(acc[1][0][2*p], acc[1][0][2*p+1]),
                         fmaxf(acc[1][1][2*p], acc[1][1][2*p+1])));
      px[p] = m + bb;
      s += px[p]; s2 += px[p]*px[p];
    }
    *(float4*)(out + (((size_t)oc*4 + pz)*4 + py)*256 + lane*4) =
        make_float4(px[0], px[1], px[2], px[3]);
    #pragma unroll
    for (int d = 32; d > 0; d >>= 1){ s += __shfl_down(s, d); s2 += __shfl_down(s2, d); }
    if (lane == 0){
      int pi = oc*16 + sp;
      part[(size_t)pi*2] = s; part[(size_t)pi*2+1] = s2;
    }
  }
}

// ============ conv2: 32->64; XCD swizzle; 8 waves = Px × ic-quarter; icl UNROLLED +
// clamped rows + uniform weight-zeroing ============
__global__ __launch_bounds__(512) void conv2t_kernel(const float* __restrict__ p1t, // [32][4][4][64][4]
                                                     const float* __restrict__ w,
                                                     const float* __restrict__ bias,
                                                     const float* __restrict__ sc,
                                                     const float* __restrict__ sh,
                                                     float* __restrict__ out)  // [64*8][64] = p2t
{
  __shared__ float red[6*8*64];          // 12 KB: icq=1..3 partials for each Px
  int bid = blockIdx.x;                  // 0..255
  int l = (bid & 7)*32 + (bid >> 3);     // 256 = 8*32, q-major logical
  int oc = l & 63;
  int q  = l >> 6;                       // 0..3
  int Pz = q >> 1, Py = q & 1;
  int tid = threadIdx.x;
  int wid = tid >> 6, lane = tid & 63;
  int Px = wid >> 2, icq = wid & 3;

  float acc[2][2][2];
  #pragma unroll
  for (int i=0;i<2;i++)
    #pragma unroll
    for (int j=0;j<2;j++)
      #pragma unroll
      for (int k=0;k<2;k++) acc[i][j][k]=0.f;

  const float* wbp = w + (size_t)oc*32*27;
  #pragma unroll
  for (int icl = 0; icl < 8; icl++){
    int ic = icq*8 + icl;
    float wr[27];
    #pragma unroll
    for (int k = 0; k < 27; k++) wr[k] = wbp[ic*27 + k];
    float s1v = sc[ic], h1v = sh[ic];
    #pragma unroll
    for (int zl = 0; zl < 4; zl++){
      int gz = 2*Pz - 1 + zl;            // [-1..4]
      bool vz = ((unsigned)gz < 4u);
      int gzc = vz ? gz : (gz < 0 ? 0 : 3);
      #pragma unroll
      for (int yl = 0; yl < 4; yl++){
        int gy = 2*Py - 1 + yl;          // [-1..4]
        bool v = vz && ((unsigned)gy < 4u);
        int gyc = ((unsigned)gy < 4u) ? gy : (gy < 0 ? 0 : 3);
        float4 f = *(const float4*)(p1t + (((size_t)ic*4 + gzc)*4 + gyc)*256 + lane*4);
        float b0 = leaky(fmaf(f.x, s1v, h1v));
        float b1 = leaky(fmaf(f.y, s1v, h1v));
        float b2 = leaky(fmaf(f.z, s1v, h1v));
        float b3 = leaky(fmaf(f.w, s1v, h1v));
        float win[4];
        if (Px == 0){ win[0]=0.f; win[1]=b0; win[2]=b1; win[3]=b2; }
        else        { win[0]=b1;  win[1]=b2; win[2]=b3; win[3]=0.f; }
        #pragma unroll
        for (int czl = 0; czl < 2; czl++){
          const int dz = zl - czl; if (dz < 0 || dz > 2) continue;
          #pragma unroll
          for (int cyl = 0; cyl < 2; cyl++){
            const int dy = yl - cyl; if (dy < 0 || dy > 2) continue;
            const int wb = dz*9 + dy*3;
            const float w0 = v ? wr[wb]   : 0.f;   // uniform select (SALU)
            const float w1 = v ? wr[wb+1] : 0.f;
            const float w2 = v ? wr[wb+2] : 0.f;
            #pragma unroll
            for (int cxl = 0; cxl < 2; cxl++){
              float a = acc[czl][cyl][cxl];
              a = fmaf(win[cxl],   w0, a);
              a = fmaf(win[cxl+1], w1, a);
              a = fmaf(win[cxl+2], w2, a);
              acc[czl][cyl][cxl] = a;
            }
          }
        }
      }
    }
  }
  if (icq > 0){
    #pragma unroll
    for (int i=0;i<2;i++)
      #pragma unroll
      for (int j=0;j<2;j++)
        #pragma unroll
        for (int k=0;k<2;k++)
          red[(((Px*3 + icq-1)*8) + (i*2+j)*2 + k)*64 + lane] = acc[i][j][k];
  }
  __syncthreads();
  if (icq == 0){
    #pragma unroll
    for (int qq = 0; qq < 3; qq++)
      #pragma unroll
      for (int i=0;i<2;i++)
        #pragma unroll
        for (int j=0;j<2;j++)
          #pragma unroll
          for (int k=0;k<2;k++)
            acc[i][j][k] += red[(((Px*3 + qq)*8) + (i*2+j)*2 + k)*64 + lane];

    float bb = bias[oc];
    float m = fmaxf(fmaxf(acc[0][0][0], acc[0][0][1]), fmaxf(acc[0][1][0], acc[0][1][1]));
    m = fmaxf(m, fmaxf(fmaxf(acc[1][0][0], acc[1][0][1]), fmaxf(acc[1][1][0], acc[1][1][1])));
    out[((size_t)oc*8 + Pz*4 + Py*2 + Px)*64 + lane] = m + bb;
  }
}

// ---------------- stats finalize: per-channel partials -> scale/shift ----------------
template<int C, int N>
__global__ __launch_bounds__(256) void stats_final(const float* __restrict__ part,
                                                   float* __restrict__ scale,
                                                   float* __restrict__ shift,
                                                   const float* __restrict__ g,
                                                   const float* __restrict__ bb,
                                                   float n)
{
  int c = blockIdx.x;
  float s = 0.f, s2 = 0.f;
  for (int i = threadIdx.x; i < N; i += 256){
    s  += part[(size_t)(c*N + i)*2];
    s2 += part[(size_t)(c*N + i)*2 + 1];
  }
  #pragma unroll
  for (int d = 32; d > 0; d >>= 1){ s += __shfl_down(s, d); s2 += __shfl_down(s2, d); }
  __shared__ float rs[4], rq[4];
  int lane = threadIdx.x & 63, wid = threadIdx.x >> 6;
  if (lane == 0){ rs[wid] = s; rq[wid] = s2; }
  __syncthreads();
  if (threadIdx.x == 0){
    float ts = rs[0]+rs[1]+rs[2]+rs[3];
    float tq = rq[0]+rq[1]+rq[2]+rq[3];
    float m = ts / n;
    float var = tq / n - m*m;
    float is = rsqrtf(var + 1e-5f);
    float scv = is * g[c];
    scale[c] = scv;
    shift[c] = bb[c] - m * scv;
  }
}

// ---------------- BN2 stats on transposed p2t: one wave per channel ----------------
__global__ __launch_bounds__(256) void bn2t_kernel(const float* __restrict__ p2t,
                                                   const float* __restrict__ g,
                                                   const float* __restrict__ bb,
                                                   float* __restrict__ scale,
                                                   float* __restrict__ shift)
{
  int gt = blockIdx.x*256 + threadIdx.x;
  int c = gt >> 6, lane = gt & 63;
  if (c >= 64) return;
  const float* p = p2t + (size_t)c*512;
  float s = 0.f, s2 = 0.f;
  #pragma unroll
  for (int i = 0; i < 8; i++){ float v = p[i*64 + lane]; s += v; s2 += v*v; }
  #pragma unroll
  for (int d = 32; d > 0; d >>= 1){ s += __shfl_down(s, d); s2 += __shfl_down(s2, d); }
  if (lane == 0){
    float m = s * (1.f/512.f);
    float var = s2 * (1.f/512.f) - m*m;
    float scv = rsqrtf(var + 1e-5f) * g[c];
    scale[c] = scv;
    shift[c] = bb[c] - m*scv;
  }
}

// ---------------- fc0: block per feature, 4 waves K-split + BN2-on-load + batch-BN3 ----------------
__global__ __launch_bounds__(256) void fc0bn_kernel(const float* __restrict__ p2t,
                                                    const float* __restrict__ W,
                                                    const float* __restrict__ bias,
                                                    const float* __restrict__ sc,
                                                    const float* __restrict__ sh,
                                                    const float* __restrict__ g,
                                                    const float* __restrict__ bb,
                                                    float* __restrict__ y0t)
{
  __shared__ float red[3][64];
  int f = blockIdx.x;                    // 0..511
  int wid = threadIdx.x >> 6, r = threadIdx.x & 63;
  const float* wr = W + (size_t)f*512;
  float a = 0.f;
  for (int c = wid*16; c < wid*16 + 16; c++){
    float s = sc[c], h = sh[c];
    #pragma unroll
    for (int jj = 0; jj < 8; jj++){
      int i = c*8 + jj;
      float xv = leaky(fmaf(p2t[(size_t)i*64 + r], s, h));
      a = fmaf(xv, wr[i], a);
    }
  }
  if (wid > 0) red[wid-1][r] = a;
  __syncthreads();
  if (wid == 0){
    a += red[0][r] + red[1][r] + red[2][r] + bias[f];
    float s1 = a, s2 = a*a;
    #pragma unroll
    for (int d = 32; d > 0; d >>= 1){ s1 += __shfl_down(s1, d); s2 += __shfl_down(s2, d); }
    s1 = __shfl(s1, 0); s2 = __shfl(s2, 0);
    float m = s1 * (1.f/64.f);
    float var = s2 * (1.f/64.f) - m*m;
    float is = rsqrtf(var + 1e-5f);
    y0t[(size_t)f*64 + r] = leaky((a - m) * is * g[f] + bb[f]);
  }
}

// ---------------- fc1: block per feature, 8 waves K-split + batch-BN4 ----------------
__global__ __launch_bounds__(512) void fc1bn_kernel(const float* __restrict__ y0t,
                                                    const float* __restrict__ W,
                                                    const float* __restrict__ bias,
                                                    const float* __restrict__ g,
                                                    const float* __restrict__ bb,
                                                    float* __restrict__ y1t)
{
  __shared__ float red[7][64];
  int f = blockIdx.x;                    // 0..255
  int wid = threadIdx.x >> 6, r = threadIdx.x & 63;
  const float* wr = W + (size_t)f*512;
  float a = 0.f;
  #pragma unroll 8
  for (int i = wid*64; i < wid*64 + 64; i++)
    a = fmaf(y0t[(size_t)i*64 + r], wr[i], a);
  if (wid > 0) red[wid-1][r] = a;
  __syncthreads();
  if (wid == 0){
    #pragma unroll
    for (int q = 0; q < 7; q++) a += red[q][r];
    a += bias[f];
    float s1 = a, s2 = a*a;
    #pragma unroll
    for (int d = 32; d > 0; d >>= 1){ s1 += __shfl_down(s1, d); s2 += __shfl_down(s2, d); }
    s1 = __shfl(s1, 0); s2 = __shfl(s2, 0);
    float m = s1 * (1.f/64.f);
    float var = s2 * (1.f/64.f) - m*m;
    float is = rsqrtf(var + 1e-5f);
    y1t[(size_t)f*64 + r] = leaky((a - m) * is * g[f] + bb[f]);
  }
}

// ---------------- fc2: block per feature, 4 waves K-split + leaky ----------------
__global__ __launch_bounds__(256) void fc2_kernel(const float* __restrict__ y1t,
                                                  const float* __restrict__ W,
                                                  const float* __restrict__ bias,
                                                  float* __restrict__ y2t)
{
  __shared__ float red[3][64];
  int f = blockIdx.x;                    // 0..99
  int wid = threadIdx.x >> 6, r = threadIdx.x & 63;
  const float* wr = W + (size_t)f*256;
  float a = 0.f;
  #pragma unroll 8
  for (int i = wid*64; i < wid*64 + 64; i++)
    a = fmaf(y1t[(size_t)i*64 + r], wr[i], a);
  if (wid > 0) red[wid-1][r] = a;
  __syncthreads();
  if (wid == 0){
    a += red[0][r] + red[1][r] + red[2][r];
    y2t[(size_t)f*64 + r] = leaky(a + bias[f]);
  }
}

// ---------------- head (100->20), wave/output ----------------
__global__ __launch_bounds__(256) void head_kernel(const float* __restrict__ y2t,
                                                   const float* __restrict__ W,
                                                   const float* __restrict__ bias,
                                                   float* __restrict__ out)
{
  int gt = blockIdx.x*256 + threadIdx.x;
  int oo = gt >> 6, r = gt & 63;
  if (oo >= 20) return;
  const float* wr = W + (size_t)oo*100;
  float a = 0.f;
  #pragma unroll 4
  for (int i = 0; i < 100; i++)
    a = fmaf(y2t[(size_t)i*64 + r], wr[i], a);
  out[(size_t)r*20 + oo] = a + bias[oo];
}

extern "C" void kernel_launch(void* const* d_in, const int* in_sizes, int n_in,
                              void* d_out, int out_size, void* d_ws, size_t ws_size,
                              hipStream_t stream)
{
  const float* x   = (const float*)d_in[0];
  const float* cw0 = (const float*)d_in[2];  const float* cb0 = (const float*)d_in[3];
  const float* g0  = (const float*)d_in[4];  const float* bb0 = (const float*)d_in[5];
  const float* cw1 = (const float*)d_in[6];  const float* cb1 = (const float*)d_in[7];
  const float* g1  = (const float*)d_in[8];  const float* bb1 = (const float*)d_in[9];
  const float* cw2 = (const float*)d_in[10]; const float* cb2 = (const float*)d_in[11];
  const float* g2  = (const float*)d_in[12]; const float* bb2 = (const float*)d_in[13];
  const float* mw0 = (const float*)d_in[14]; const float* mb0 = (const float*)d_in[15];
  const float* g3  = (const float*)d_in[16]; const float* bb3 = (const float*)d_in[17];
  const float* mw1 = (const float*)d_in[18]; const float* mb1 = (const float*)d_in[19];
  const float* g4  = (const float*)d_in[20]; const float* bb4 = (const float*)d_in[21];
  const float* mw2 = (const float*)d_in[22]; const float* mb2 = (const float*)d_in[23];
  const float* hw  = (const float*)d_in[24]; const float* hb  = (const float*)d_in[25];

  float* ws     = (float*)d_ws;
  // Region A (2488320): tab during blur (first 2097152), then ft [6][18][18][5][64][4]
  float* tab    = ws;
  float* ft     = ws;
  int*   dst    = (int*)(ws + 2097152);  // tail of A, dead before ft is written
  int*   sstart = dst + 32768;
  int*   scount = sstart + 384;
  // Region B (2239488): fields during blur, then p0t [16][9][9][3][64][4] (995328)
  float* fields = ws + 2488320;
  float* p0t    = fields;
  float* rest   = fields + 2239488;
  float* p1t    = rest;                  // 131072  [32][4][4][64][4]
  float* p2t    = p1t + 131072;          // 32768   [512][64]
  float* y0t    = p2t + 32768;           // 32768
  float* y1t    = y0t + 32768;           // 16384
  float* y2t    = y1t + 16384;           // 6400
  float* part   = y2t + 6400;            // 6144 (max 16*162*2 = 5184)
  float* sc0    = part + 6144;           // 16
  float* sh0    = sc0 + 16;
  float* sc1    = sh0 + 16;              // 32
  float* sh1    = sc1 + 32;
  float* sc2    = sh1 + 32;              // 64
  float* sh2    = sc2 + 64;
  float* outp   = (float*)d_out;

  atom_sort<<<64, 64, 0, stream>>>(x, dst, sstart, scount);
  blur_prep<<<128, 256, 0, stream>>>(x, dst, tab);
  blur_accum<<<768, 192, 0, stream>>>(tab, sstart, scount, fields);
  transpose_fields<<<216, 256, 0, stream>>>(fields, ft);

  conv0t_kernel<<<2592, 64, 0, stream>>>(ft, cw0, cb0, p0t, part);
  stats_final<16,162><<<16, 256, 0, stream>>>(part, sc0, sh0, g0, bb0, 64.f*729.f);

  conv1t_kernel<<<512, 256, 0, stream>>>(p0t, cw1, cb1, sc0, sh0, p1t, part);
  stats_final<32,16><<<32, 256, 0, stream>>>(part, sc1, sh1, g1, bb1, 64.f*64.f);

  conv2t_kernel<<<256, 512, 0, stream>>>(p1t, cw2, cb2, sc1, sh1, p2t);
  bn2t_kernel<<<16, 256, 0, stream>>>(p2t, g2, bb2, sc2, sh2);

  fc0bn_kernel<<<512, 256, 0, stream>>>(p2t, mw0, mb0, sc2, sh2, g3, bb3, y0t);
  fc1bn_kernel<<<256, 512, 0, stream>>>(y0t, mw1, mb1, g4, bb4, y1t);
  fc2_kernel<<<100, 256, 0, stream>>>(y1t, mw2, mb2, y2t);
  head_kernel<<<5, 256, 0, stream>>>(y2t, hw, hb, outp);
}

// Round 20
// 154.365 us; speedup vs baseline: 1.1135x; 1.0666x over previous
//
#include <hip/hip_runtime.h>
#include <math.h>

#define BATCH 64
#define APB 512
#define NA 6
#define NG 5832  // 18^3

__device__ __forceinline__ float leaky(float v){ return v >= 0.f ? v : 0.01f*v; }

// ============ atom sort: deterministic counting sort by (batch, type) ============
__global__ __launch_bounds__(64) void atom_sort(const float* __restrict__ x,
                                                int* __restrict__ dst,
                                                int* __restrict__ seg_start,
                                                int* __restrict__ seg_count)
{
  int batch = blockIdx.x;
  int lane  = threadIdx.x;
  int tyc[8];
  int cnt[NA];
  #pragma unroll
  for (int t = 0; t < NA; t++) cnt[t] = 0;
  #pragma unroll
  for (int c = 0; c < 8; c++){
    int a = batch*APB + c*64 + lane;
    int ty = (int)x[(size_t)a*5 + 1];
    tyc[c] = ty;
    #pragma unroll
    for (int t = 0; t < NA; t++){
      unsigned long long m = __ballot(ty == t);
      cnt[t] += __popcll(m);
    }
  }
  int pre[NA+1];
  pre[0] = 0;
  #pragma unroll
  for (int t = 0; t < NA; t++) pre[t+1] = pre[t] + cnt[t];
  if (lane < NA){
    seg_start[batch*NA + lane] = batch*APB + pre[lane];
    seg_count[batch*NA + lane] = cnt[lane];
  }
  int run[NA];
  #pragma unroll
  for (int t = 0; t < NA; t++) run[t] = pre[t];
  unsigned long long below = (lane == 0) ? 0ull : ((~0ull) >> (64 - lane));
  #pragma unroll
  for (int c = 0; c < 8; c++){
    int a = batch*APB + c*64 + lane;
    int ty = tyc[c];
    int rank = 0;
    #pragma unroll
    for (int t = 0; t < NA; t++){
      unsigned long long m = __ballot(ty == t);
      if (ty == t) rank = run[t] + __popcll(m & below);
      run[t] += __popcll(m);
    }
    dst[a] = batch*APB + rank;
  }
}

// ============ blur phase 1: per-atom separable 1-D tables (sorted rows) ============
__global__ __launch_bounds__(256) void blur_prep(const float* __restrict__ x,
                                                 const int* __restrict__ dst,
                                                 float* __restrict__ tab)
{
  int a = blockIdx.x*256 + threadIdx.x;
  if (a >= BATCH*APB) return;
  const float* row = x + (size_t)a*5;
  float p0 = row[2], p1 = row[3], p2 = row[4];
  float e[54];
  float s0 = 0.f, s1 = 0.f, s2 = 0.f;
  #pragma unroll
  for (int i = 0; i < 18; i++){
    float g = (float)i - 8.5f;
    float d0 = p0 - g, d1 = p1 - g, d2 = p2 - g;
    float v0 = __expf(d0*d0 * (-1.f/0.72f));
    float v1 = __expf(d1*d1 * (-1.f/0.72f));
    float v2 = __expf(d2*d2 * (-1.f/0.72f));
    e[i] = v0; e[18+i] = v1; e[36+i] = v2;
    s0 += v0; s1 += v1; s2 += v2;
  }
  float inv = 1.f / (s0*s1*s2 + 1e-6f);
  float* tp = tab + (size_t)dst[a]*64;
  #pragma unroll
  for (int i = 0; i < 18; i++) tp[i] = e[i]*inv;
  tp[18] = 0.f; tp[19] = 0.f;
  #pragma unroll
  for (int i = 0; i < 18; i++) tp[20+i] = e[18+i];
  #pragma unroll
  for (int i = 0; i < 18; i++) tp[40+i] = e[36+i];
}

// ============ blur phase 2: branch-free streaming outer-product; writes ft DIRECTLY ============
// ft offset = (((t*18+z)*18+y)*5 + xq)*256 + b*4 + xr ; x slots 18,19 zero.
__global__ __launch_bounds__(192) void blur_accum(const float* __restrict__ tab,
                                                  const int* __restrict__ seg_start,
                                                  const int* __restrict__ seg_count,
                                                  float* __restrict__ ft)
{
  int bid  = blockIdx.x;
  int seg  = bid >> 1;
  int half = bid & 1;
  int batch = seg / NA, t = seg - batch*NA;
  int tid = threadIdx.x;
  bool act = tid < 162;
  int ix = half*9 + tid/18;            // z-dim of the 18^3 cell (outer meshgrid axis)
  int iy = tid % 18;                   // y-dim

  float acc[18];
  #pragma unroll
  for (int k = 0; k < 18; k++) acc[k] = 0.f;

  int start = seg_start[seg], count = seg_count[seg];
  const float* tb = tab + (size_t)start*64;

  int j = 0;
  for (; j + 3 < count; j += 4){
    const float* t0 = tb + (size_t)(j+0)*64;
    const float* t1 = tb + (size_t)(j+1)*64;
    const float* t2 = tb + (size_t)(j+2)*64;
    const float* t3 = tb + (size_t)(j+3)*64;
    float e0 = t0[ix]*t0[20+iy];
    float e1 = t1[ix]*t1[20+iy];
    float e2 = t2[ix]*t2[20+iy];
    float e3 = t3[ix]*t3[20+iy];
    #pragma unroll
    for (int k = 0; k < 18; k++){
      float a = acc[k];
      a = fmaf(e0, t0[40+k], a);
      a = fmaf(e1, t1[40+k], a);
      a = fmaf(e2, t2[40+k], a);
      a = fmaf(e3, t3[40+k], a);
      acc[k] = a;
    }
  }
  for (; j < count; j++){
    const float* t0 = tb + (size_t)j*64;
    float e0 = t0[ix]*t0[20+iy];
    #pragma unroll
    for (int k = 0; k < 18; k++)
      acc[k] = fmaf(e0, t0[40+k], acc[k]);
  }
  if (act){
    float* fo = ft + ((((size_t)t*18 + ix)*18 + iy)*5)*256 + (size_t)batch*4;
    *(float4*)(fo)        = make_float4(acc[0],  acc[1],  acc[2],  acc[3]);
    *(float4*)(fo + 256)  = make_float4(acc[4],  acc[5],  acc[6],  acc[7]);
    *(float4*)(fo + 512)  = make_float4(acc[8],  acc[9],  acc[10], acc[11]);
    *(float4*)(fo + 768)  = make_float4(acc[12], acc[13], acc[14], acc[15]);
    *(float4*)(fo + 1024) = make_float4(acc[16], acc[17], 0.f, 0.f);
  }
}

// ============ conv0: 6->16; single wave per (oc,sp,xh); xh branch hoisted; straight-line ============
__global__ __launch_bounds__(64) void conv0t_kernel(const float* __restrict__ ft,
                                                    const float* __restrict__ w,
                                                    const float* __restrict__ bias,
                                                    float* __restrict__ out,   // [16][9][9][3xq][64][4]
                                                    float* __restrict__ part)  // [16*162][2]
{
  int bid = blockIdx.x;                  // 0..2591
  int l = (bid & 7)*324 + (bid >> 3);    // XCD-aware bijection (2592 = 8*324)
  int oc = l & 15, xh = (l >> 4) & 1;
  int sp = l >> 5;                       // 0..80
  int pz = sp / 9, py = sp - pz*9;
  int lane = threadIdx.x;

  float acc[2][2][10];
  #pragma unroll
  for (int i=0;i<2;i++)
    #pragma unroll
    for (int j=0;j<2;j++)
      #pragma unroll
      for (int k=0;k<10;k++) acc[i][j][k]=0.f;

  float bb = bias[oc];
  float s = 0.f, s2 = 0.f;
  float* op = out + (((size_t)oc*9 + pz)*9 + py)*3*256 + lane*4;

  if (xh == 0){
    #pragma unroll
    for (int ic = 0; ic < 6; ic++){
      float wr[27];
      #pragma unroll
      for (int k = 0; k < 27; k++) wr[k] = w[(oc*6+ic)*27 + k];
      #pragma unroll
      for (int zl = 0; zl < 4; zl++){
        int gz = 2*pz - 1 + zl;
        bool vz = ((unsigned)gz < 18u);
        int gzc = vz ? gz : (gz < 0 ? 0 : 17);
        #pragma unroll
        for (int yl = 0; yl < 4; yl++){
          int gy = 2*py - 1 + yl;
          bool v = vz && ((unsigned)gy < 18u);
          int gyc = ((unsigned)gy < 18u) ? gy : (gy < 0 ? 0 : 17);
          const float* rp = ft + (((size_t)ic*18 + gzc)*18 + gyc)*5*256 + lane*4;
          float4 A0 = *(const float4*)(rp);
          float4 A1 = *(const float4*)(rp + 256);
          float4 A2 = *(const float4*)(rp + 512);
          float xv[13];
          xv[0] = 0.f;
          *(float4*)&xv[1] = A0; *(float4*)&xv[5] = A1; *(float4*)&xv[9] = A2;
          #pragma unroll
          for (int czl = 0; czl < 2; czl++){
            const int dz = zl - czl; if (dz < 0 || dz > 2) continue;
            #pragma unroll
            for (int cyl = 0; cyl < 2; cyl++){
              const int dy = yl - cyl; if (dy < 0 || dy > 2) continue;
              const int wb = dz*9 + dy*3;
              const float w0 = v ? wr[wb]   : 0.f;   // uniform select (SALU)
              const float w1 = v ? wr[wb+1] : 0.f;
              const float w2 = v ? wr[wb+2] : 0.f;
              #pragma unroll
              for (int cx = 0; cx < 10; cx++){
                float a = acc[czl][cyl][cx];
                a = fmaf(xv[cx],   w0, a);
                a = fmaf(xv[cx+1], w1, a);
                a = fmaf(xv[cx+2], w2, a);
                acc[czl][cyl][cx] = a;
              }
            }
          }
        }
      }
    }
    float px[5];
    #pragma unroll
    for (int p = 0; p < 5; p++){
      float m = fmaxf(fmaxf(acc[0][0][2*p], acc[0][0][2*p+1]),
                      fmaxf(acc[0][1][2*p], acc[0][1][2*p+1]));
      m = fmaxf(m, fmaxf(fmaxf(acc[1][0][2*p], acc[1][0][2*p+1]),
                         fmaxf(acc[1][1][2*p], acc[1][1][2*p+1])));
      px[p] = m + bb;
      s += px[p]; s2 += px[p]*px[p];
    }
    *(float4*)(op) = make_float4(px[0], px[1], px[2], px[3]);
    op[256] = px[4];
  } else {
    #pragma unroll
    for (int ic = 0; ic < 6; ic++){
      float wr[27];
      #pragma unroll
      for (int k = 0; k < 27; k++) wr[k] = w[(oc*6+ic)*27 + k];
      #pragma unroll
      for (int zl = 0; zl < 4; zl++){
        int gz = 2*pz - 1 + zl;
        bool vz = ((unsigned)gz < 18u);
        int gzc = vz ? gz : (gz < 0 ? 0 : 17);
        #pragma unroll
        for (int yl = 0; yl < 4; yl++){
          int gy = 2*py - 1 + yl;
          bool v = vz && ((unsigned)gy < 18u);
          int gyc = ((unsigned)gy < 18u) ? gy : (gy < 0 ? 0 : 17);
          const float* rp = ft + (((size_t)ic*18 + gzc)*18 + gyc)*5*256 + lane*4;
          float4 A2 = *(const float4*)(rp + 512);
          float4 A3 = *(const float4*)(rp + 768);
          float4 A4 = *(const float4*)(rp + 1024);
          float win[12];                            // win[j] = p(9+j); p18,p19 stored zero
          *(float4*)&win[0] = A2; *(float4*)&win[4] = A3; *(float4*)&win[8] = A4;
          #pragma unroll
          for (int czl = 0; czl < 2; czl++){
            const int dz = zl - czl; if (dz < 0 || dz > 2) continue;
            #pragma unroll
            for (int cyl = 0; cyl < 2; cyl++){
              const int dy = yl - cyl; if (dy < 0 || dy > 2) continue;
              const int wb = dz*9 + dy*3;
              const float w0 = v ? wr[wb]   : 0.f;
              const float w1 = v ? wr[wb+1] : 0.f;
              const float w2 = v ? wr[wb+2] : 0.f;
              #pragma unroll
              for (int cl = 0; cl < 8; cl++){       // cx = 10+cl
                float a = acc[czl][cyl][cl];
                a = fmaf(win[cl+1], w0, a);
                a = fmaf(win[cl+2], w1, a);
                a = fmaf(win[cl+3], w2, a);
                acc[czl][cyl][cl] = a;
              }
            }
          }
        }
      }
    }
    float px[4];
    #pragma unroll
    for (int p = 0; p < 4; p++){   // px = 5+p
      float m = fmaxf(fmaxf(acc[0][0][2*p], acc[0][0][2*p+1]),
                      fmaxf(acc[0][1][2*p], acc[0][1][2*p+1]));
      m = fmaxf(m, fmaxf(fmaxf(acc[1][0][2*p], acc[1][0][2*p+1]),
                         fmaxf(acc[1][1][2*p], acc[1][1][2*p+1])));
      px[p] = m + bb;
      s += px[p]; s2 += px[p]*px[p];
    }
    op[256+1] = px[0]; op[256+2] = px[1]; op[256+3] = px[2]; op[512] = px[3];
  }
  #pragma unroll
  for (int d = 32; d > 0; d >>= 1){ s += __shfl_down(s, d); s2 += __shfl_down(s2, d); }
  if (lane == 0){
    int pi = oc*162 + sp*2 + xh;
    part[(size_t)pi*2] = s; part[(size_t)pi*2+1] = s2;
  }
}

// ============ conv1: 16->32; XCD swizzle; 4 waves = ic-quarters; icl UNROLLED ============
__global__ __launch_bounds__(256) void conv1t_kernel(const float* __restrict__ p0t, // [16][9][9][3][64][4]
                                                     const float* __restrict__ w,
                                                     const float* __restrict__ bias,
                                                     const float* __restrict__ sc,
                                                     const float* __restrict__ sh,
                                                     float* __restrict__ out,   // [32][4][4][64][4]
                                                     float* __restrict__ part)  // [32*16][2]
{
  __shared__ float red[3*32*64];
  int bid = blockIdx.x;                  // 0..511
  int l = (bid & 7)*64 + (bid >> 3);     // 512 = 8*64, sp-major logical
  int oc = l & 31;
  int sp = l >> 5;                       // 0..15
  int pz = sp >> 2, py = sp & 3;
  int tid = threadIdx.x;
  int wid = tid >> 6, lane = tid & 63;

  float acc[2][2][8];
  #pragma unroll
  for (int i=0;i<2;i++)
    #pragma unroll
    for (int j=0;j<2;j++)
      #pragma unroll
      for (int k=0;k<8;k++) acc[i][j][k]=0.f;

  const float* wbp = w + (size_t)oc*16*27;
  #pragma unroll
  for (int icl = 0; icl < 4; icl++){
    int ic = wid*4 + icl;
    float wr[27];
    #pragma unroll
    for (int k = 0; k < 27; k++) wr[k] = wbp[ic*27 + k];
    float s0v = sc[ic], h0v = sh[ic];
    #pragma unroll
    for (int zl = 0; zl < 4; zl++){
      int gz = 2*pz - 1 + zl;            // [-1..8]
      bool vz = ((unsigned)gz < 9u);
      int gzc = vz ? gz : 0;
      #pragma unroll
      for (int yl = 0; yl < 4; yl++){
        int gy = 2*py - 1 + yl;          // [-1..8]
        bool v = vz && ((unsigned)gy < 9u);
        int gyc = ((unsigned)gy < 9u) ? gy : 0;
        const float* rp = p0t + (((size_t)ic*9 + gzc)*9 + gyc)*3*256 + lane*4;
        float4 A0 = *(const float4*)(rp);
        float4 A1 = *(const float4*)(rp + 256);
        float  A2 = rp[512];
        float xv[10];
        xv[0]=0.f;
        xv[1]=leaky(fmaf(A0.x, s0v, h0v)); xv[2]=leaky(fmaf(A0.y, s0v, h0v));
        xv[3]=leaky(fmaf(A0.z, s0v, h0v)); xv[4]=leaky(fmaf(A0.w, s0v, h0v));
        xv[5]=leaky(fmaf(A1.x, s0v, h0v)); xv[6]=leaky(fmaf(A1.y, s0v, h0v));
        xv[7]=leaky(fmaf(A1.z, s0v, h0v)); xv[8]=leaky(fmaf(A1.w, s0v, h0v));
        xv[9]=leaky(fmaf(A2,   s0v, h0v));
        #pragma unroll
        for (int czl = 0; czl < 2; czl++){
          const int dz = zl - czl; if (dz < 0 || dz > 2) continue;
          #pragma unroll
          for (int cyl = 0; cyl < 2; cyl++){
            const int dy = yl - cyl; if (dy < 0 || dy > 2) continue;
            const int wb = dz*9 + dy*3;
            const float w0 = v ? wr[wb]   : 0.f;
            const float w1 = v ? wr[wb+1] : 0.f;
            const float w2 = v ? wr[wb+2] : 0.f;
            #pragma unroll
            for (int cx = 0; cx < 8; cx++){
              float a = acc[czl][cyl][cx];
              a = fmaf(xv[cx],   w0, a);
              a = fmaf(xv[cx+1], w1, a);
              a = fmaf(xv[cx+2], w2, a);
              acc[czl][cyl][cx] = a;
            }
          }
        }
      }
    }
  }
  if (wid > 0){
    #pragma unroll
    for (int i=0;i<2;i++)
      #pragma unroll
      for (int j=0;j<2;j++)
        #pragma unroll
        for (int k=0;k<8;k++)
          red[(((wid-1)*32) + (i*2+j)*8 + k)*64 + lane] = acc[i][j][k];
  }
  __syncthreads();
  if (wid == 0){
    #pragma unroll
    for (int q = 0; q < 3; q++)
      #pragma unroll
      for (int i=0;i<2;i++)
        #pragma unroll
        for (int j=0;j<2;j++)
          #pragma unroll
          for (int k=0;k<8;k++)
            acc[i][j][k] += red[((q*32) + (i*2+j)*8 + k)*64 + lane];

    float bb = bias[oc];
    float px[4];
    float s = 0.f, s2 = 0.f;
    #pragma unroll
    for (int p = 0; p < 4; p++){
      float m = fmaxf(fmaxf(acc[0][0][2*p], acc[0][0][2*p+1]),
                      fmaxf(acc[0][1][2*p], acc[0][1][2*p+1]));
      m = fmaxf(m, fmaxf(fmaxf(acc[1][0][2*p], acc[1][0][2*p+1]),
                         fmaxf(acc[1][1][2*p], acc[1][1][2*p+1])));
      px[p] = m + bb;
      s += px[p]; s2 += px[p]*px[p];
    }
    *(float4*)(out + (((size_t)oc*4 + pz)*4 + py)*256 + lane*4) =
        make_float4(px[0], px[1], px[2], px[3]);
    #pragma unroll
    for (int d = 32; d > 0; d >>= 1){ s += __shfl_down(s, d); s2 += __shfl_down(s2, d); }
    if (lane == 0){
      int pi = oc*16 + sp;
      part[(size_t)pi*2] = s; part[(size_t)pi*2+1] = s2;
    }
  }
}

// ============ conv2: 32->64; XCD swizzle; 8 waves = Px × ic-quarter; icl UNROLLED +
// clamped rows + uniform weight-zeroing ============
__global__ __launch_bounds__(512) void conv2t_kernel(const float* __restrict__ p1t, // [32][4][4][64][4]
                                                     const float* __restrict__ w,
                                                     const float* __restrict__ bias,
                                                     const float* __restrict__ sc,
                                                     const float* __restrict__ sh,
                                                     float* __restrict__ out)  // [64*8][64] = p2t
{
  __shared__ float red[6*8*64];          // 12 KB: icq=1..3 partials for each Px
  int bid = blockIdx.x;                  // 0..255
  int l = (bid & 7)*32 + (bid >> 3);     // 256 = 8*32, q-major logical
  int oc = l & 63;
  int q  = l >> 6;                       // 0..3
  int Pz = q >> 1, Py = q & 1;
  int tid = threadIdx.x;
  int wid = tid >> 6, lane = tid & 63;
  int Px = wid >> 2, icq = wid & 3;

  float acc[2][2][2];
  #pragma unroll
  for (int i=0;i<2;i++)
    #pragma unroll
    for (int j=0;j<2;j++)
      #pragma unroll
      for (int k=0;k<2;k++) acc[i][j][k]=0.f;

  const float* wbp = w + (size_t)oc*32*27;
  #pragma unroll
  for (int icl = 0; icl < 8; icl++){
    int ic = icq*8 + icl;
    float wr[27];
    #pragma unroll
    for (int k = 0; k < 27; k++) wr[k] = wbp[ic*27 + k];
    float s1v = sc[ic], h1v = sh[ic];
    #pragma unroll
    for (int zl = 0; zl < 4; zl++){
      int gz = 2*Pz - 1 + zl;            // [-1..4]
      bool vz = ((unsigned)gz < 4u);
      int gzc = vz ? gz : (gz < 0 ? 0 : 3);
      #pragma unroll
      for (int yl = 0; yl < 4; yl++){
        int gy = 2*Py - 1 + yl;          // [-1..4]
        bool v = vz && ((unsigned)gy < 4u);
        int gyc = ((unsigned)gy < 4u) ? gy : (gy < 0 ? 0 : 3);
        float4 f = *(const float4*)(p1t + (((size_t)ic*4 + gzc)*4 + gyc)*256 + lane*4);
        float b0 = leaky(fmaf(f.x, s1v, h1v));
        float b1 = leaky(fmaf(f.y, s1v, h1v));
        float b2 = leaky(fmaf(f.z, s1v, h1v));
        float b3 = leaky(fmaf(f.w, s1v, h1v));
        float win[4];
        if (Px == 0){ win[0]=0.f; win[1]=b0; win[2]=b1; win[3]=b2; }
        else        { win[0]=b1;  win[1]=b2; win[2]=b3; win[3]=0.f; }
        #pragma unroll
        for (int czl = 0; czl < 2; czl++){
          const int dz = zl - czl; if (dz < 0 || dz > 2) continue;
          #pragma unroll
          for (int cyl = 0; cyl < 2; cyl++){
            const int dy = yl - cyl; if (dy < 0 || dy > 2) continue;
            const int wb = dz*9 + dy*3;
            const float w0 = v ? wr[wb]   : 0.f;   // uniform select (SALU)
            const float w1 = v ? wr[wb+1] : 0.f;
            const float w2 = v ? wr[wb+2] : 0.f;
            #pragma unroll
            for (int cxl = 0; cxl < 2; cxl++){
              float a = acc[czl][cyl][cxl];
              a = fmaf(win[cxl],   w0, a);
              a = fmaf(win[cxl+1], w1, a);
              a = fmaf(win[cxl+2], w2, a);
              acc[czl][cyl][cxl] = a;
            }
          }
        }
      }
    }
  }
  if (icq > 0){
    #pragma unroll
    for (int i=0;i<2;i++)
      #pragma unroll
      for (int j=0;j<2;j++)
        #pragma unroll
        for (int k=0;k<2;k++)
          red[(((Px*3 + icq-1)*8) + (i*2+j)*2 + k)*64 + lane] = acc[i][j][k];
  }
  __syncthreads();
  if (icq == 0){
    #pragma unroll
    for (int qq = 0; qq < 3; qq++)
      #pragma unroll
      for (int i=0;i<2;i++)
        #pragma unroll
        for (int j=0;j<2;j++)
          #pragma unroll
          for (int k=0;k<2;k++)
            acc[i][j][k] += red[(((Px*3 + qq)*8) + (i*2+j)*2 + k)*64 + lane];

    float bb = bias[oc];
    float m = fmaxf(fmaxf(acc[0][0][0], acc[0][0][1]), fmaxf(acc[0][1][0], acc[0][1][1]));
    m = fmaxf(m, fmaxf(fmaxf(acc[1][0][0], acc[1][0][1]), fmaxf(acc[1][1][0], acc[1][1][1])));
    out[((size_t)oc*8 + Pz*4 + Py*2 + Px)*64 + lane] = m + bb;
  }
}

// ---------------- stats finalize: per-channel partials -> scale/shift ----------------
template<int C, int N>
__global__ __launch_bounds__(256) void stats_final(const float* __restrict__ part,
                                                   float* __restrict__ scale,
                                                   float* __restrict__ shift,
                                                   const float* __restrict__ g,
                                                   const float* __restrict__ bb,
                                                   float n)
{
  int c = blockIdx.x;
  float s = 0.f, s2 = 0.f;
  for (int i = threadIdx.x; i < N; i += 256){
    s  += part[(size_t)(c*N + i)*2];
    s2 += part[(size_t)(c*N + i)*2 + 1];
  }
  #pragma unroll
  for (int d = 32; d > 0; d >>= 1){ s += __shfl_down(s, d); s2 += __shfl_down(s2, d); }
  __shared__ float rs[4], rq[4];
  int lane = threadIdx.x & 63, wid = threadIdx.x >> 6;
  if (lane == 0){ rs[wid] = s; rq[wid] = s2; }
  __syncthreads();
  if (threadIdx.x == 0){
    float ts = rs[0]+rs[1]+rs[2]+rs[3];
    float tq = rq[0]+rq[1]+rq[2]+rq[3];
    float m = ts / n;
    float var = tq / n - m*m;
    float is = rsqrtf(var + 1e-5f);
    float scv = is * g[c];
    scale[c] = scv;
    shift[c] = bb[c] - m * scv;
  }
}

// ---------------- BN2 stats on transposed p2t: one wave per channel ----------------
__global__ __launch_bounds__(256) void bn2t_kernel(const float* __restrict__ p2t,
                                                   const float* __restrict__ g,
                                                   const float* __restrict__ bb,
                                                   float* __restrict__ scale,
                                                   float* __restrict__ shift)
{
  int gt = blockIdx.x*256 + threadIdx.x;
  int c = gt >> 6, lane = gt & 63;
  if (c >= 64) return;
  const float* p = p2t + (size_t)c*512;
  float s = 0.f, s2 = 0.f;
  #pragma unroll
  for (int i = 0; i < 8; i++){ float v = p[i*64 + lane]; s += v; s2 += v*v; }
  #pragma unroll
  for (int d = 32; d > 0; d >>= 1){ s += __shfl_down(s, d); s2 += __shfl_down(s2, d); }
  if (lane == 0){
    float m = s * (1.f/512.f);
    float var = s2 * (1.f/512.f) - m*m;
    float scv = rsqrtf(var + 1e-5f) * g[c];
    scale[c] = scv;
    shift[c] = bb[c] - m*scv;
  }
}

// ---------------- fc0: block per feature, 4 waves K-split + BN2-on-load + batch-BN3 ----------------
__global__ __launch_bounds__(256) void fc0bn_kernel(const float* __restrict__ p2t,
                                                    const float* __restrict__ W,
                                                    const float* __restrict__ bias,
                                                    const float* __restrict__ sc,
                                                    const float* __restrict__ sh,
                                                    const float* __restrict__ g,
                                                    const float* __restrict__ bb,
                                                    float* __restrict__ y0t)
{
  __shared__ float red[3][64];
  int f = blockIdx.x;                    // 0..511
  int wid = threadIdx.x >> 6, r = threadIdx.x & 63;
  const float* wr = W + (size_t)f*512;
  float a = 0.f;
  for (int c = wid*16; c < wid*16 + 16; c++){
    float s = sc[c], h = sh[c];
    #pragma unroll
    for (int jj = 0; jj < 8; jj++){
      int i = c*8 + jj;
      float xv = leaky(fmaf(p2t[(size_t)i*64 + r], s, h));
      a = fmaf(xv, wr[i], a);
    }
  }
  if (wid > 0) red[wid-1][r] = a;
  __syncthreads();
  if (wid == 0){
    a += red[0][r] + red[1][r] + red[2][r] + bias[f];
    float s1 = a, s2 = a*a;
    #pragma unroll
    for (int d = 32; d > 0; d >>= 1){ s1 += __shfl_down(s1, d); s2 += __shfl_down(s2, d); }
    s1 = __shfl(s1, 0); s2 = __shfl(s2, 0);
    float m = s1 * (1.f/64.f);
    float var = s2 * (1.f/64.f) - m*m;
    float is = rsqrtf(var + 1e-5f);
    y0t[(size_t)f*64 + r] = leaky((a - m) * is * g[f] + bb[f]);
  }
}

// ---------------- fc1: block per feature, 8 waves K-split + batch-BN4 ----------------
__global__ __launch_bounds__(512) void fc1bn_kernel(const float* __restrict__ y0t,
                                                    const float* __restrict__ W,
                                                    const float* __restrict__ bias,
                                                    const float* __restrict__ g,
                                                    const float* __restrict__ bb,
                                                    float* __restrict__ y1t)
{
  __shared__ float red[7][64];
  int f = blockIdx.x;                    // 0..255
  int wid = threadIdx.x >> 6, r = threadIdx.x & 63;
  const float* wr = W + (size_t)f*512;
  float a = 0.f;
  #pragma unroll 8
  for (int i = wid*64; i < wid*64 + 64; i++)
    a = fmaf(y0t[(size_t)i*64 + r], wr[i], a);
  if (wid > 0) red[wid-1][r] = a;
  __syncthreads();
  if (wid == 0){
    #pragma unroll
    for (int q = 0; q < 7; q++) a += red[q][r];
    a += bias[f];
    float s1 = a, s2 = a*a;
    #pragma unroll
    for (int d = 32; d > 0; d >>= 1){ s1 += __shfl_down(s1, d); s2 += __shfl_down(s2, d); }
    s1 = __shfl(s1, 0); s2 = __shfl(s2, 0);
    float m = s1 * (1.f/64.f);
    float var = s2 * (1.f/64.f) - m*m;
    float is = rsqrtf(var + 1e-5f);
    y1t[(size_t)f*64 + r] = leaky((a - m) * is * g[f] + bb[f]);
  }
}

// ---------------- fc2: block per feature, 4 waves K-split + leaky ----------------
__global__ __launch_bounds__(256) void fc2_kernel(const float* __restrict__ y1t,
                                                  const float* __restrict__ W,
                                                  const float* __restrict__ bias,
                                                  float* __restrict__ y2t)
{
  __shared__ float red[3][64];
  int f = blockIdx.x;                    // 0..99
  int wid = threadIdx.x >> 6, r = threadIdx.x & 63;
  const float* wr = W + (size_t)f*256;
  float a = 0.f;
  #pragma unroll 8
  for (int i = wid*64; i < wid*64 + 64; i++)
    a = fmaf(y1t[(size_t)i*64 + r], wr[i], a);
  if (wid > 0) red[wid-1][r] = a;
  __syncthreads();
  if (wid == 0){
    a += red[0][r] + red[1][r] + red[2][r];
    y2t[(size_t)f*64 + r] = leaky(a + bias[f]);
  }
}

// ---------------- head (100->20), wave/output ----------------
__global__ __launch_bounds__(256) void head_kernel(const float* __restrict__ y2t,
                                                   const float* __restrict__ W,
                                                   const float* __restrict__ bias,
                                                   float* __restrict__ out)
{
  int gt = blockIdx.x*256 + threadIdx.x;
  int oo = gt >> 6, r = gt & 63;
  if (oo >= 20) return;
  const float* wr = W + (size_t)oo*100;
  float a = 0.f;
  #pragma unroll 4
  for (int i = 0; i < 100; i++)
    a = fmaf(y2t[(size_t)i*64 + r], wr[i], a);
  out[(size_t)r*20 + oo] = a + bias[oo];
}

extern "C" void kernel_launch(void* const* d_in, const int* in_sizes, int n_in,
                              void* d_out, int out_size, void* d_ws, size_t ws_size,
                              hipStream_t stream)
{
  const float* x   = (const float*)d_in[0];
  const float* cw0 = (const float*)d_in[2];  const float* cb0 = (const float*)d_in[3];
  const float* g0  = (const float*)d_in[4];  const float* bb0 = (const float*)d_in[5];
  const float* cw1 = (const float*)d_in[6];  const float* cb1 = (const float*)d_in[7];
  const float* g1  = (const float*)d_in[8];  const float* bb1 = (const float*)d_in[9];
  const float* cw2 = (const float*)d_in[10]; const float* cb2 = (const float*)d_in[11];
  const float* g2  = (const float*)d_in[12]; const float* bb2 = (const float*)d_in[13];
  const float* mw0 = (const float*)d_in[14]; const float* mb0 = (const float*)d_in[15];
  const float* g3  = (const float*)d_in[16]; const float* bb3 = (const float*)d_in[17];
  const float* mw1 = (const float*)d_in[18]; const float* mb1 = (const float*)d_in[19];
  const float* g4  = (const float*)d_in[20]; const float* bb4 = (const float*)d_in[21];
  const float* mw2 = (const float*)d_in[22]; const float* mb2 = (const float*)d_in[23];
  const float* hw  = (const float*)d_in[24]; const float* hb  = (const float*)d_in[25];

  float* ws     = (float*)d_ws;
  // Region A (2488320 floats): during blur = tab[2097152] + sort ints;
  // after blur_accum completes it is reused for p0t and all small buffers.
  float* tab    = ws;
  int*   dst    = (int*)(ws + 2097152);
  int*   sstart = dst + 32768;
  int*   scount = sstart + 384;
  float* p0t    = ws;                    // 995328  [16][9][9][3][64][4] (after blur)
  float* p1t    = ws + 995328;           // 131072  [32][4][4][64][4]
  float* p2t    = p1t + 131072;          // 32768   [512][64]
  float* y0t    = p2t + 32768;           // 32768
  float* y1t    = y0t + 32768;           // 16384
  float* y2t    = y1t + 16384;           // 6400
  float* part   = y2t + 6400;            // 6144 (max 16*162*2 = 5184)
  float* sc0    = part + 6144;           // 16
  float* sh0    = sc0 + 16;
  float* sc1    = sh0 + 16;              // 32
  float* sh1    = sc1 + 32;
  float* sc2    = sh1 + 32;              // 64
  float* sh2    = sc2 + 64;
  // Region B (2488320 floats): ft [6][18][18][5][64][4], written directly by blur_accum
  float* ft     = ws + 2488320;
  float* outp   = (float*)d_out;

  atom_sort<<<64, 64, 0, stream>>>(x, dst, sstart, scount);
  blur_prep<<<128, 256, 0, stream>>>(x, dst, tab);
  blur_accum<<<768, 192, 0, stream>>>(tab, sstart, scount, ft);

  conv0t_kernel<<<2592, 64, 0, stream>>>(ft, cw0, cb0, p0t, part);
  stats_final<16,162><<<16, 256, 0, stream>>>(part, sc0, sh0, g0, bb0, 64.f*729.f);

  conv1t_kernel<<<512, 256, 0, stream>>>(p0t, cw1, cb1, sc0, sh0, p1t, part);
  stats_final<32,16><<<32, 256, 0, stream>>>(part, sc1, sh1, g1, bb1, 64.f*64.f);

  conv2t_kernel<<<256, 512, 0, stream>>>(p1t, cw2, cb2, sc1, sh1, p2t);
  bn2t_kernel<<<16, 256, 0, stream>>>(p2t, g2, bb2, sc2, sh2);

  fc0bn_kernel<<<512, 256, 0, stream>>>(p2t, mw0, mb0, sc2, sh2, g3, bb3, y0t);
  fc1bn_kernel<<<256, 512, 0, stream>>>(y0t, mw1, mb1, g4, bb4, y1t);
  fc2_kernel<<<100, 256, 0, stream>>>(y1t, mw2, mb2, y2t);
  head_kernel<<<5, 256, 0, stream>>>(y2t, hw, hb, outp);
}